// Round 1
// baseline (748.495 us; speedup 1.0000x reference)
//
#include <hip/hip_runtime.h>
#include <hip/hip_bf16.h>

typedef __attribute__((ext_vector_type(4))) float f32x4;
typedef __attribute__((ext_vector_type(8))) short short8;

static __device__ __forceinline__ unsigned short f2bf(float f) {
  unsigned u = __builtin_bit_cast(unsigned, f);
  u += 0x7FFFu + ((u >> 16) & 1u);
  return (unsigned short)(u >> 16);
}
static __device__ __forceinline__ float bf2f(unsigned short h) {
  unsigned u = ((unsigned)h) << 16;
  return __builtin_bit_cast(float, u);
}

// ---------------- CSR build ----------------
__global__ void hist_kernel(const int* __restrict__ dst, int* __restrict__ cnt, int E) {
  int i = blockIdx.x * blockDim.x + threadIdx.x;
  if (i < E) atomicAdd(&cnt[dst[i]], 1);
}

__global__ __launch_bounds__(1024) void scan_kernel(const int* __restrict__ cnt,
                                                    int* __restrict__ row_ptr, int n) {
  __shared__ int wsum[16];
  __shared__ int carry;
  int tid = threadIdx.x;
  int lane = tid & 63, w = tid >> 6;
  if (tid == 0) carry = 0;
  __syncthreads();
  for (int base = 0; base < n; base += 1024) {
    int i = base + tid;
    int v = (i < n) ? cnt[i] : 0;
    int incl = v;
    #pragma unroll
    for (int off = 1; off < 64; off <<= 1) {
      int t = __shfl_up(incl, off, 64);
      if (lane >= off) incl += t;
    }
    if (lane == 63) wsum[w] = incl;
    __syncthreads();
    if (tid == 0) {
      int run = carry;
      #pragma unroll
      for (int q = 0; q < 16; ++q) { int t = wsum[q]; wsum[q] = run; run += t; }
      carry = run;
    }
    __syncthreads();
    if (i < n) row_ptr[i] = wsum[w] + incl - v;
    __syncthreads();
  }
  if (tid == 0) row_ptr[n] = carry;
}

__global__ void fill_kernel(const int* __restrict__ src, const int* __restrict__ dst,
                            const int* __restrict__ row_ptr, int* __restrict__ cursor,
                            int* __restrict__ col, int E) {
  int i = blockIdx.x * blockDim.x + threadIdx.x;
  if (i < E) {
    int d = dst[i];
    int pos = atomicAdd(&cursor[d], 1);
    col[row_ptr[d] + pos] = src[i];
  }
}

// ---------------- SpMM: agg[r] = sum_{c in row r} h[c] ----------------
__global__ __launch_bounds__(256) void spmm_kernel(const float* __restrict__ h,
                                                   const int* __restrict__ row_ptr,
                                                   const int* __restrict__ col,
                                                   float* __restrict__ agg, int N) {
  int row = blockIdx.x * 4 + (threadIdx.x >> 6);
  if (row >= N) return;
  int lane = threadIdx.x & 63;
  int s = row_ptr[row], e = row_ptr[row + 1];
  const float2* hp = (const float2*)h;
  float2 acc = make_float2(0.f, 0.f);
  int i = s;
  for (; i + 1 < e; i += 2) {
    int c0 = col[i], c1 = col[i + 1];
    float2 v0 = hp[(size_t)c0 * 64 + lane];
    float2 v1 = hp[(size_t)c1 * 64 + lane];
    acc.x += v0.x; acc.y += v0.y;
    acc.x += v1.x; acc.y += v1.y;
  }
  if (i < e) {
    int c0 = col[i];
    float2 v0 = hp[(size_t)c0 * 64 + lane];
    acc.x += v0.x; acc.y += v0.y;
  }
  ((float2*)agg)[(size_t)row * 64 + lane] = acc;
}

// ---------------- weight prep: Wcat^T in bf16 hi/lo ----------------
// Wt[col][k], k in [0,256): k<128 -> W_rel[k][col], k>=128 -> W_root[k-128][col]
__global__ void prep_kernel(const float* __restrict__ Wrel, const float* __restrict__ Wroot,
                            short* __restrict__ Whi, short* __restrict__ Wlo) {
  int idx = blockIdx.x * blockDim.x + threadIdx.x;  // 0..32767 = col*256 + k
  int col = idx >> 8;
  int k = idx & 255;
  float v = (k < 128) ? Wrel[k * 128 + col] : Wroot[(k - 128) * 128 + col];
  unsigned short hi = f2bf(v);
  unsigned short lo = f2bf(v - bf2f(hi));
  Whi[idx] = (short)hi;
  Wlo[idx] = (short)lo;
}

// ---------------- fused GEMM: out = relu(concat[agg,h] @ Wcat + b) ----------------
__global__ __launch_bounds__(256) void gemm_kernel(const float* __restrict__ Aagg,
                                                   const float* __restrict__ Ah,
                                                   const short* __restrict__ Whi,
                                                   const short* __restrict__ Wlo,
                                                   const float* __restrict__ bias,
                                                   float* __restrict__ out, int N) {
  int wv = threadIdx.x >> 6;
  int lane = threadIdx.x & 63;
  int l16 = lane & 15;
  int khalf = lane >> 4;  // 0..3
  int koff = khalf * 8;
  int row_base = blockIdx.x * 64;
  int col_base = wv * 32;

  f32x4 acc[4][2];
  #pragma unroll
  for (int r = 0; r < 4; r++)
    #pragma unroll
    for (int c = 0; c < 2; c++) acc[r][c] = (f32x4){0.f, 0.f, 0.f, 0.f};

  #pragma unroll
  for (int ks = 0; ks < 8; ++ks) {
    int k0 = ks * 32;
    const float* Abase = (ks < 4) ? (Aagg + k0) : (Ah + (k0 - 128));
    short8 bh[2], bl[2];
    #pragma unroll
    for (int c = 0; c < 2; c++) {
      int col = col_base + c * 16 + l16;
      bh[c] = *(const short8*)(Whi + col * 256 + k0 + koff);
      bl[c] = *(const short8*)(Wlo + col * 256 + k0 + koff);
    }
    #pragma unroll
    for (int r = 0; r < 4; r++) {
      int row = row_base + r * 16 + l16;
      if (row >= N) row = N - 1;
      const float* ap = Abase + (size_t)row * 128 + koff;
      float4 v0 = *(const float4*)ap;
      float4 v1 = *(const float4*)(ap + 4);
      float vv[8] = {v0.x, v0.y, v0.z, v0.w, v1.x, v1.y, v1.z, v1.w};
      short8 ah, al;
      #pragma unroll
      for (int t = 0; t < 8; t++) {
        unsigned short h = f2bf(vv[t]);
        ah[t] = (short)h;
        al[t] = (short)f2bf(vv[t] - bf2f(h));
      }
      #pragma unroll
      for (int c = 0; c < 2; c++) {
        acc[r][c] = __builtin_amdgcn_mfma_f32_16x16x32_bf16(ah, bh[c], acc[r][c], 0, 0, 0);
        acc[r][c] = __builtin_amdgcn_mfma_f32_16x16x32_bf16(al, bh[c], acc[r][c], 0, 0, 0);
        acc[r][c] = __builtin_amdgcn_mfma_f32_16x16x32_bf16(ah, bl[c], acc[r][c], 0, 0, 0);
      }
    }
  }

  #pragma unroll
  for (int r = 0; r < 4; r++) {
    #pragma unroll
    for (int c = 0; c < 2; c++) {
      int col = col_base + c * 16 + l16;
      float b = bias[col];
      #pragma unroll
      for (int t = 0; t < 4; t++) {
        int row = row_base + r * 16 + khalf * 4 + t;
        if (row < N) {
          float v = acc[r][c][t] + b;
          out[(size_t)row * 128 + col] = v > 0.f ? v : 0.f;
        }
      }
    }
  }
}

// ---------------- global add pool ----------------
__global__ __launch_bounds__(256) void pool_kernel(const float* __restrict__ h,
                                                   const int* __restrict__ batch,
                                                   float* __restrict__ g, int N) {
  int row = blockIdx.x * 4 + (threadIdx.x >> 6);
  if (row >= N) return;
  int lane = threadIdx.x & 63;
  int b = batch[row];
  float2 v = ((const float2*)h)[(size_t)row * 64 + lane];
  atomicAdd(&g[b * 128 + lane * 2], v.x);
  atomicAdd(&g[b * 128 + lane * 2 + 1], v.y);
}

// ---------------- MLP head ----------------
__global__ __launch_bounds__(128) void head_kernel(const float* __restrict__ g,
                                                   const float* __restrict__ fc1W,
                                                   const float* __restrict__ fc1b,
                                                   const float* __restrict__ fc2W,
                                                   const float* __restrict__ fc2b,
                                                   float* __restrict__ out, int G) {
  int gid = blockIdx.x;
  int j = threadIdx.x;  // 0..127
  __shared__ float row[128];
  __shared__ float red[128];
  row[j] = g[(size_t)gid * 128 + j];
  __syncthreads();
  float acc = fc1b[j];
  #pragma unroll 8
  for (int k = 0; k < 128; ++k) acc = fmaf(row[k], fc1W[k * 128 + j], acc);
  acc = acc > 0.f ? acc : 0.f;
  red[j] = acc * fc2W[j];
  __syncthreads();
  #pragma unroll
  for (int s = 64; s > 0; s >>= 1) {
    if (j < s) red[j] += red[j + s];
    __syncthreads();
  }
  if (j == 0) out[gid] = red[0] + fc2b[0];
}

extern "C" void kernel_launch(void* const* d_in, const int* in_sizes, int n_in,
                              void* d_out, int out_size, void* d_ws, size_t ws_size,
                              hipStream_t stream) {
  const float* x = (const float*)d_in[0];
  const int* edge = (const int*)d_in[1];
  const int* batch = (const int*)d_in[2];
  const int N = in_sizes[0] / 128;
  const int E = in_sizes[1] / 2;
  const int G = out_size;  // output is [G,1]
  const int* esrc = edge;
  const int* edst = edge + E;

  char* ws = (char*)d_ws;
  size_t off = 0;
  auto alloc = [&](size_t bytes) -> void* {
    void* p = ws + off;
    off = (off + bytes + 255) & ~(size_t)255;
    return p;
  };
  float* bufA = (float*)alloc((size_t)N * 128 * 4);
  float* bufB = (float*)alloc((size_t)N * 128 * 4);
  float* agg  = (float*)alloc((size_t)N * 128 * 4);
  float* gbuf = (float*)alloc((size_t)G * 128 * 4);
  short* Whi  = (short*)alloc((size_t)5 * 32768 * 2);
  short* Wlo  = (short*)alloc((size_t)5 * 32768 * 2);
  int* row_ptr = (int*)alloc((size_t)(N + 1) * 4);
  int* cnt     = (int*)alloc((size_t)N * 4);
  int* cursor  = (int*)alloc((size_t)N * 4);
  int* col     = (int*)alloc((size_t)E * 4);
  if (off > ws_size) return;  // workspace too small: fail loudly (poisoned output)

  hipMemsetAsync(cnt, 0, (size_t)N * 4, stream);
  hipMemsetAsync(cursor, 0, (size_t)N * 4, stream);
  hipMemsetAsync(gbuf, 0, (size_t)G * 128 * 4, stream);

  int eb = (E + 255) / 256;
  hist_kernel<<<eb, 256, 0, stream>>>(edst, cnt, E);
  scan_kernel<<<1, 1024, 0, stream>>>(cnt, row_ptr, N);
  fill_kernel<<<eb, 256, 0, stream>>>(esrc, edst, row_ptr, cursor, col, E);

  for (int l = 0; l < 5; ++l) {
    prep_kernel<<<128, 256, 0, stream>>>((const float*)d_in[4 + 3 * l],
                                         (const float*)d_in[6 + 3 * l],
                                         Whi + (size_t)l * 32768, Wlo + (size_t)l * 32768);
  }

  const float* hin = x;
  float* hout = bufA;
  int spmm_grid = (N + 3) / 4;
  int gemm_grid = (N + 63) / 64;
  for (int l = 0; l < 5; ++l) {
    spmm_kernel<<<spmm_grid, 256, 0, stream>>>(hin, row_ptr, col, agg, N);
    gemm_kernel<<<gemm_grid, 256, 0, stream>>>(agg, hin,
                                               Whi + (size_t)l * 32768, Wlo + (size_t)l * 32768,
                                               (const float*)d_in[5 + 3 * l], hout, N);
    hin = hout;
    hout = (hout == bufA) ? bufB : bufA;
  }
  pool_kernel<<<spmm_grid, 256, 0, stream>>>(hin, batch, gbuf, N);
  head_kernel<<<G, 128, 0, stream>>>(gbuf, (const float*)d_in[19], (const float*)d_in[20],
                                     (const float*)d_in[21], (const float*)d_in[22],
                                     (float*)d_out, G);
}

// Round 3
// 505.601 us; speedup vs baseline: 1.4804x; 1.4804x over previous
//
#include <hip/hip_runtime.h>
#include <hip/hip_bf16.h>

typedef __attribute__((ext_vector_type(4))) float f32x4;
typedef __attribute__((ext_vector_type(8))) _Float16 f16x8;
typedef __attribute__((ext_vector_type(4))) _Float16 f16x4;

static __device__ __forceinline__ float2 h2f2(unsigned v) {
  _Float16 lo = __builtin_bit_cast(_Float16, (unsigned short)(v & 0xffffu));
  _Float16 hi = __builtin_bit_cast(_Float16, (unsigned short)(v >> 16));
  return make_float2((float)lo, (float)hi);
}
static __device__ __forceinline__ unsigned f2h2(float x, float y) {
  unsigned short lo = __builtin_bit_cast(unsigned short, (_Float16)x);
  unsigned short hi = __builtin_bit_cast(unsigned short, (_Float16)y);
  return ((unsigned)hi << 16) | lo;
}

// ---------------- fp32 -> fp16 convert ----------------
__global__ __launch_bounds__(256) void cvt_kernel(const float* __restrict__ x,
                                                  _Float16* __restrict__ h, int total4) {
  int i = blockIdx.x * blockDim.x + threadIdx.x;
  if (i < total4) {
    float4 v = *(const float4*)(x + (size_t)i * 4);
    f16x4 o = {(_Float16)v.x, (_Float16)v.y, (_Float16)v.z, (_Float16)v.w};
    *(f16x4*)(h + (size_t)i * 4) = o;
  }
}

// ---------------- CSR build ----------------
__global__ void hist_kernel(const int* __restrict__ dst, int* __restrict__ cnt, int E) {
  int i = blockIdx.x * blockDim.x + threadIdx.x;
  if (i < E) atomicAdd(&cnt[dst[i]], 1);
}

__global__ __launch_bounds__(1024) void scan1_kernel(const int* __restrict__ cnt,
                                                     int* __restrict__ row_ptr,
                                                     int* __restrict__ blksum, int n) {
  __shared__ int wsum[16];
  int tid = threadIdx.x, lane = tid & 63, w = tid >> 6;
  int base = blockIdx.x * 4096 + tid * 4;
  int v0 = 0, v1 = 0, v2 = 0, v3 = 0;
  if (base + 3 < n) {
    int4 t = *(const int4*)(cnt + base);
    v0 = t.x; v1 = t.y; v2 = t.z; v3 = t.w;
  } else {
    if (base + 0 < n) v0 = cnt[base + 0];
    if (base + 1 < n) v1 = cnt[base + 1];
    if (base + 2 < n) v2 = cnt[base + 2];
    if (base + 3 < n) v3 = cnt[base + 3];
  }
  int s = v0 + v1 + v2 + v3;
  int incl = s;
  #pragma unroll
  for (int off = 1; off < 64; off <<= 1) {
    int t = __shfl_up(incl, off, 64);
    if (lane >= off) incl += t;
  }
  if (lane == 63) wsum[w] = incl;
  __syncthreads();
  if (tid == 0) {
    int run = 0;
    #pragma unroll
    for (int q = 0; q < 16; ++q) { int t = wsum[q]; wsum[q] = run; run += t; }
    blksum[blockIdx.x] = run;
  }
  __syncthreads();
  int excl = wsum[w] + incl - s;
  if (base + 0 < n) row_ptr[base + 0] = excl;
  if (base + 1 < n) row_ptr[base + 1] = excl + v0;
  if (base + 2 < n) row_ptr[base + 2] = excl + v0 + v1;
  if (base + 3 < n) row_ptr[base + 3] = excl + v0 + v1 + v2;
}

__global__ void scan2_kernel(int* __restrict__ blksum, int nb, int* __restrict__ total) {
  if (threadIdx.x == 0 && blockIdx.x == 0) {
    int run = 0;
    for (int i = 0; i < nb; ++i) { int t = blksum[i]; blksum[i] = run; run += t; }
    *total = run;
  }
}

__global__ __launch_bounds__(1024) void scan3_kernel(int* __restrict__ row_ptr,
                                                     const int* __restrict__ blksum,
                                                     const int* __restrict__ total, int n) {
  int base = blockIdx.x * 4096 + threadIdx.x * 4;
  int off = blksum[blockIdx.x];
  #pragma unroll
  for (int t = 0; t < 4; ++t)
    if (base + t < n) row_ptr[base + t] += off;
  if (blockIdx.x == 0 && threadIdx.x == 0) row_ptr[n] = *total;
}

__global__ void fill_kernel(const int* __restrict__ src, const int* __restrict__ dst,
                            const int* __restrict__ row_ptr, int* __restrict__ cursor,
                            int* __restrict__ col, int E) {
  int i = blockIdx.x * blockDim.x + threadIdx.x;
  if (i < E) {
    int d = dst[i];
    int pos = atomicAdd(&cursor[d], 1);
    col[row_ptr[d] + pos] = src[i];
  }
}

// ---------------- SpMM (fp16 gather): agg[r] = sum_{c in row r} h[c] ----------------
__global__ __launch_bounds__(256) void spmm_kernel(const unsigned* __restrict__ h2,
                                                   const int* __restrict__ row_ptr,
                                                   const int* __restrict__ col,
                                                   unsigned* __restrict__ agg2, int N) {
  int row = blockIdx.x * 4 + (threadIdx.x >> 6);
  if (row >= N) return;
  int lane = threadIdx.x & 63;
  int s = row_ptr[row], e = row_ptr[row + 1];
  float ax = 0.f, ay = 0.f;
  int i = s;
  for (; i + 3 < e; i += 4) {
    int c0 = col[i], c1 = col[i + 1], c2 = col[i + 2], c3 = col[i + 3];
    unsigned v0 = h2[(size_t)c0 * 64 + lane];
    unsigned v1 = h2[(size_t)c1 * 64 + lane];
    unsigned v2 = h2[(size_t)c2 * 64 + lane];
    unsigned v3 = h2[(size_t)c3 * 64 + lane];
    float2 f0 = h2f2(v0), f1 = h2f2(v1), f2 = h2f2(v2), f3 = h2f2(v3);
    ax += f0.x + f1.x + f2.x + f3.x;
    ay += f0.y + f1.y + f2.y + f3.y;
  }
  for (; i < e; ++i) {
    float2 f0 = h2f2(h2[(size_t)col[i] * 64 + lane]);
    ax += f0.x; ay += f0.y;
  }
  agg2[(size_t)row * 64 + lane] = f2h2(ax, ay);
}

// ---------------- weight prep: Wcat^T in f16 hi/lo, scaled by wscale ----------------
__global__ void prep_kernel(const float* __restrict__ Wrel, const float* __restrict__ Wroot,
                            _Float16* __restrict__ Whi, _Float16* __restrict__ Wlo,
                            float wscale) {
  int idx = blockIdx.x * blockDim.x + threadIdx.x;  // col*256 + k
  int col = idx >> 8;
  int k = idx & 255;
  float v = (k < 128) ? Wrel[k * 128 + col] : Wroot[(k - 128) * 128 + col];
  v *= wscale;
  _Float16 hi = (_Float16)v;
  _Float16 lo = (_Float16)(v - (float)hi);
  Whi[idx] = hi;
  Wlo[idx] = lo;
}

// ---------------- fused GEMM: out = relu(concat[agg,h] @ Wcat + b*bscale), fp16 ----------------
__global__ __launch_bounds__(256) void gemm_kernel(const _Float16* __restrict__ Aagg,
                                                   const _Float16* __restrict__ Ah,
                                                   const _Float16* __restrict__ Whi,
                                                   const _Float16* __restrict__ Wlo,
                                                   const float* __restrict__ bias,
                                                   float bscale,
                                                   _Float16* __restrict__ out, int N) {
  int wv = threadIdx.x >> 6;
  int lane = threadIdx.x & 63;
  int l16 = lane & 15;
  int khalf = lane >> 4;  // 0..3
  int koff = khalf * 8;
  int row_base = blockIdx.x * 64;
  int col_base = wv * 32;

  f32x4 acc[4][2];
  #pragma unroll
  for (int r = 0; r < 4; r++)
    #pragma unroll
    for (int c = 0; c < 2; c++) acc[r][c] = (f32x4){0.f, 0.f, 0.f, 0.f};

  #pragma unroll
  for (int ks = 0; ks < 8; ++ks) {
    int k0 = ks * 32;
    const _Float16* Abase = (ks < 4) ? (Aagg + k0) : (Ah + (k0 - 128));
    f16x8 bh[2], bl[2];
    #pragma unroll
    for (int c = 0; c < 2; c++) {
      int col = col_base + c * 16 + l16;
      bh[c] = *(const f16x8*)(Whi + col * 256 + k0 + koff);
      bl[c] = *(const f16x8*)(Wlo + col * 256 + k0 + koff);
    }
    #pragma unroll
    for (int r = 0; r < 4; r++) {
      int row = row_base + r * 16 + l16;
      if (row >= N) row = N - 1;
      f16x8 a = *(const f16x8*)(Abase + (size_t)row * 128 + koff);
      #pragma unroll
      for (int c = 0; c < 2; c++) {
        acc[r][c] = __builtin_amdgcn_mfma_f32_16x16x32_f16(a, bh[c], acc[r][c], 0, 0, 0);
        acc[r][c] = __builtin_amdgcn_mfma_f32_16x16x32_f16(a, bl[c], acc[r][c], 0, 0, 0);
      }
    }
  }

  #pragma unroll
  for (int r = 0; r < 4; r++) {
    #pragma unroll
    for (int c = 0; c < 2; c++) {
      int col = col_base + c * 16 + l16;
      float b = bias[col] * bscale;
      #pragma unroll
      for (int t = 0; t < 4; t++) {
        int row = row_base + r * 16 + khalf * 4 + t;
        if (row < N) {
          float v = acc[r][c][t] + b;
          out[(size_t)row * 128 + col] = (_Float16)(v > 0.f ? v : 0.f);
        }
      }
    }
  }
}

// ---------------- global add pool (batch sorted: one block per graph) ----------------
static __device__ __forceinline__ int lbound(const int* __restrict__ a, int n, int v) {
  int lo = 0, hi = n;
  while (lo < hi) {
    int m = (lo + hi) >> 1;
    if (a[m] < v) lo = m + 1; else hi = m;
  }
  return lo;
}

__global__ __launch_bounds__(256) void pool_kernel(const _Float16* __restrict__ h,
                                                   const int* __restrict__ batch,
                                                   float* __restrict__ g, int N,
                                                   float unscale) {
  int gid = blockIdx.x;
  int start = lbound(batch, N, gid);
  int end = lbound(batch, N, gid + 1);
  int j = threadIdx.x & 127;    // feature
  int half = threadIdx.x >> 7;  // 0/1
  float acc = 0.f;
  for (int r = start + half; r < end; r += 2)
    acc += (float)h[(size_t)r * 128 + j];
  __shared__ float red[256];
  red[threadIdx.x] = acc;
  __syncthreads();
  if (half == 0) g[(size_t)gid * 128 + j] = (red[j] + red[128 + j]) * unscale;
}

// ---------------- MLP head ----------------
__global__ __launch_bounds__(128) void head_kernel(const float* __restrict__ g,
                                                   const float* __restrict__ fc1W,
                                                   const float* __restrict__ fc1b,
                                                   const float* __restrict__ fc2W,
                                                   const float* __restrict__ fc2b,
                                                   float* __restrict__ out, int G) {
  int gid = blockIdx.x;
  int j = threadIdx.x;  // 0..127
  __shared__ float row[128];
  __shared__ float red[128];
  row[j] = g[(size_t)gid * 128 + j];
  __syncthreads();
  float acc = fc1b[j];
  #pragma unroll 8
  for (int k = 0; k < 128; ++k) acc = fmaf(row[k], fc1W[k * 128 + j], acc);
  acc = acc > 0.f ? acc : 0.f;
  red[j] = acc * fc2W[j];
  __syncthreads();
  #pragma unroll
  for (int s = 64; s > 0; s >>= 1) {
    if (j < s) red[j] += red[j + s];
    __syncthreads();
  }
  if (j == 0) out[gid] = red[0] + fc2b[0];
}

extern "C" void kernel_launch(void* const* d_in, const int* in_sizes, int n_in,
                              void* d_out, int out_size, void* d_ws, size_t ws_size,
                              hipStream_t stream) {
  const float* x = (const float*)d_in[0];
  const int* edge = (const int*)d_in[1];
  const int* batch = (const int*)d_in[2];
  const int N = in_sizes[0] / 128;
  const int E = in_sizes[1] / 2;
  const int G = out_size;  // output is [G,1]
  const int* esrc = edge;
  const int* edst = edge + E;

  char* ws = (char*)d_ws;
  size_t off = 0;
  auto alloc = [&](size_t bytes) -> void* {
    void* p = ws + off;
    off = (off + bytes + 255) & ~(size_t)255;
    return p;
  };
  _Float16* x16  = (_Float16*)alloc((size_t)N * 128 * 2);
  _Float16* bufA = (_Float16*)alloc((size_t)N * 128 * 2);
  _Float16* bufB = (_Float16*)alloc((size_t)N * 128 * 2);
  _Float16* agg  = (_Float16*)alloc((size_t)N * 128 * 2);
  float* gbuf    = (float*)alloc((size_t)G * 128 * 4);
  _Float16* Whi  = (_Float16*)alloc((size_t)5 * 32768 * 2);
  _Float16* Wlo  = (_Float16*)alloc((size_t)5 * 32768 * 2);
  int* row_ptr   = (int*)alloc((size_t)(N + 1) * 4);
  int* cnt       = (int*)alloc((size_t)N * 4);
  int* cursor    = (int*)alloc((size_t)N * 4);
  int* col       = (int*)alloc((size_t)E * 4);
  int* blksum    = (int*)alloc(64 * 4);
  int* total     = (int*)alloc(4);
  if (off > ws_size) return;  // workspace too small: fail loudly (poisoned output)

  hipMemsetAsync(cnt, 0, (size_t)N * 4, stream);
  hipMemsetAsync(cursor, 0, (size_t)N * 4, stream);

  int eb = (E + 255) / 256;
  int nscan = (N + 4095) / 4096;
  hist_kernel<<<eb, 256, 0, stream>>>(edst, cnt, E);
  scan1_kernel<<<nscan, 1024, 0, stream>>>(cnt, row_ptr, blksum, N);
  scan2_kernel<<<1, 1, 0, stream>>>(blksum, nscan, total);
  scan3_kernel<<<nscan, 1024, 0, stream>>>(row_ptr, blksum, total, N);
  fill_kernel<<<eb, 256, 0, stream>>>(esrc, edst, row_ptr, cursor, col, E);

  cvt_kernel<<<(N * 128 / 4 + 255) / 256, 256, 0, stream>>>(x, x16, N * 128 / 4);

  // Per-layer rescale: h'_l = h_l / 8^l keeps fp16 in range (raw layer-5 agg
  // overflows fp16 at ~1.2e5 > 65504). Weights scaled 1/8, bias by 8^-(l+1),
  // undone at the fp32 pool with 8^5.
  const float S = 8.0f;
  float bscale = 1.0f;
  for (int l = 0; l < 5; ++l) {
    prep_kernel<<<128, 256, 0, stream>>>((const float*)d_in[4 + 3 * l],
                                         (const float*)d_in[6 + 3 * l],
                                         Whi + (size_t)l * 32768, Wlo + (size_t)l * 32768,
                                         1.0f / S);
  }

  const _Float16* hin = x16;
  _Float16* hout = bufA;
  int spmm_grid = (N + 3) / 4;
  int gemm_grid = (N + 63) / 64;
  for (int l = 0; l < 5; ++l) {
    bscale /= S;  // 8^-(l+1)
    spmm_kernel<<<spmm_grid, 256, 0, stream>>>((const unsigned*)hin, row_ptr, col,
                                               (unsigned*)agg, N);
    gemm_kernel<<<gemm_grid, 256, 0, stream>>>(agg, hin,
                                               Whi + (size_t)l * 32768, Wlo + (size_t)l * 32768,
                                               (const float*)d_in[5 + 3 * l], bscale, hout, N);
    hin = hout;
    hout = (hout == bufA) ? bufB : bufA;
  }
  pool_kernel<<<G, 256, 0, stream>>>(hin, batch, gbuf, N, 32768.0f);
  head_kernel<<<G, 128, 0, stream>>>(gbuf, (const float*)d_in[19], (const float*)d_in[20],
                                     (const float*)d_in[21], (const float*)d_in[22],
                                     (float*)d_out, G);
}

// Round 4
// 421.597 us; speedup vs baseline: 1.7754x; 1.1993x over previous
//
#include <hip/hip_runtime.h>
#include <hip/hip_bf16.h>

typedef __attribute__((ext_vector_type(4))) float f32x4;
typedef __attribute__((ext_vector_type(8))) _Float16 f16x8;
typedef __attribute__((ext_vector_type(4))) _Float16 f16x4;

#define CHUNK 4096   // edges per pass-1 block
#define BSH 7        // nodes per bucket = 128
#define CAP 4096     // max edges per bucket handled in LDS fast path

static __device__ __forceinline__ float2 h2f2(unsigned v) {
  _Float16 lo = __builtin_bit_cast(_Float16, (unsigned short)(v & 0xffffu));
  _Float16 hi = __builtin_bit_cast(_Float16, (unsigned short)(v >> 16));
  return make_float2((float)lo, (float)hi);
}
static __device__ __forceinline__ unsigned f2h2(float x, float y) {
  unsigned short lo = __builtin_bit_cast(unsigned short, (_Float16)x);
  unsigned short hi = __builtin_bit_cast(unsigned short, (_Float16)y);
  return ((unsigned)hi << 16) | lo;
}

// ---------------- fp32 -> fp16 convert ----------------
__global__ __launch_bounds__(256) void cvt_kernel(const float* __restrict__ x,
                                                  _Float16* __restrict__ h, int total4) {
  int i = blockIdx.x * blockDim.x + threadIdx.x;
  if (i < total4) {
    float4 v = *(const float4*)(x + (size_t)i * 4);
    f16x4 o = {(_Float16)v.x, (_Float16)v.y, (_Float16)v.z, (_Float16)v.w};
    *(f16x4*)(h + (size_t)i * 4) = o;
  }
}

// ---------------- CSR build: bucketed counting sort ----------------
// Pass 1a: per-bucket edge counts (LDS pre-aggregated)
__global__ __launch_bounds__(256) void bhist_kernel(const int* __restrict__ dst,
                                                    int* __restrict__ gcnt, int E, int nb) {
  __shared__ int l[512];
  int t = threadIdx.x;
  for (int i = t; i < 512; i += 256) l[i] = 0;
  __syncthreads();
  int cbase = blockIdx.x * CHUNK;
  #pragma unroll
  for (int i = 0; i < CHUNK / 256; ++i) {
    int idx = cbase + i * 256 + t;
    if (idx < E) atomicAdd(&l[dst[idx] >> BSH], 1);
  }
  __syncthreads();
  for (int i = t; i < nb; i += 256) {
    int c = l[i];
    if (c) atomicAdd(&gcnt[i], c);
  }
}

// Pass 1b: exclusive scan of bucket sizes -> base; init cursor=base
__global__ __launch_bounds__(512) void bscan_kernel(const int* __restrict__ gcnt,
                                                    int* __restrict__ base,
                                                    int* __restrict__ gcursor, int nb, int E) {
  __shared__ int wsum[8], wpre[8];
  int t = threadIdx.x, lane = t & 63, w = t >> 6;
  int v = (t < nb) ? gcnt[t] : 0;
  int incl = v;
  #pragma unroll
  for (int o = 1; o < 64; o <<= 1) {
    int x = __shfl_up(incl, o, 64);
    if (lane >= o) incl += x;
  }
  if (lane == 63) wsum[w] = incl;
  __syncthreads();
  if (t == 0) {
    int run = 0;
    #pragma unroll
    for (int q = 0; q < 8; ++q) { wpre[q] = run; run += wsum[q]; }
  }
  __syncthreads();
  int excl = wpre[w] + incl - v;
  if (t < nb) { base[t] = excl; gcursor[t] = excl; }
  if (t == 0) base[nb] = E;
}

// Pass 1c: scatter edges into bucket-grouped pairs array (LDS-grouped runs)
__global__ __launch_bounds__(256) void bscatter_kernel(const int* __restrict__ src,
                                                       const int* __restrict__ dst,
                                                       int* __restrict__ gcursor,
                                                       int2* __restrict__ pairs, int E, int nb) {
  __shared__ int lcnt[512], lstart[512], lpos[512], lgbase[512];
  __shared__ int2 lp[CHUNK];
  __shared__ int wsum[4], wpre[4];
  int t = threadIdx.x, lane = t & 63, w = t >> 6;
  for (int i = t; i < 512; i += 256) lcnt[i] = 0;
  __syncthreads();
  int cbase = blockIdx.x * CHUNK;
  int m = E - cbase; if (m > CHUNK) m = CHUNK;
  #pragma unroll
  for (int i = 0; i < CHUNK / 256; ++i) {
    int idx = i * 256 + t;
    if (idx < m) atomicAdd(&lcnt[dst[cbase + idx] >> BSH], 1);
  }
  __syncthreads();
  // blocked scan: thread t owns buckets 2t, 2t+1
  int c0 = lcnt[2 * t], c1 = lcnt[2 * t + 1];
  int s = c0 + c1, incl = s;
  #pragma unroll
  for (int o = 1; o < 64; o <<= 1) {
    int x = __shfl_up(incl, o, 64);
    if (lane >= o) incl += x;
  }
  if (lane == 63) wsum[w] = incl;
  __syncthreads();
  if (t == 0) {
    int run = 0;
    #pragma unroll
    for (int q = 0; q < 4; ++q) { wpre[q] = run; run += wsum[q]; }
  }
  __syncthreads();
  int excl = wpre[w] + incl - s;
  lstart[2 * t] = excl;         lpos[2 * t] = excl;
  lstart[2 * t + 1] = excl + c0; lpos[2 * t + 1] = excl + c0;
  if (2 * t < nb && c0 > 0) lgbase[2 * t] = atomicAdd(&gcursor[2 * t], c0);
  if (2 * t + 1 < nb && c1 > 0) lgbase[2 * t + 1] = atomicAdd(&gcursor[2 * t + 1], c1);
  __syncthreads();
  #pragma unroll
  for (int i = 0; i < CHUNK / 256; ++i) {
    int idx = i * 256 + t;
    if (idx < m) {
      int d = dst[cbase + idx], sv = src[cbase + idx];
      int p = atomicAdd(&lpos[d >> BSH], 1);
      lp[p] = make_int2(sv, d);
    }
  }
  __syncthreads();
  for (int i = t; i < m; i += 256) {
    int2 pr = lp[i];
    int b = pr.y >> BSH;
    pairs[lgbase[b] + (i - lstart[b])] = pr;
  }
}

// Pass 2: per-bucket local CSR; coalesced col writes; row_ptr direct
__global__ __launch_bounds__(256) void bbuild_kernel(const int2* __restrict__ pairs,
                                                     const int* __restrict__ base,
                                                     int* __restrict__ row_ptr,
                                                     int* __restrict__ col, int N, int E) {
  __shared__ int cnt[128], cur[128], w2[2];
  __shared__ int cl[CAP];
  int b = blockIdx.x, t = threadIdx.x;
  int mb = base[b], me = base[b + 1], m = me - mb;
  if (t < 128) cnt[t] = 0;
  __syncthreads();
  for (int i = t; i < m; i += 256) atomicAdd(&cnt[pairs[mb + i].y & 127], 1);
  __syncthreads();
  int v = 0, incl = 0;
  if (t < 128) {
    v = cnt[t]; incl = v;
    #pragma unroll
    for (int o = 1; o < 64; o <<= 1) {
      int x = __shfl_up(incl, o, 64);
      if ((t & 63) >= o) incl += x;
    }
    if ((t & 63) == 63) w2[t >> 6] = incl;
  }
  __syncthreads();
  if (t < 128) {
    int excl = incl - v + ((t & 64) ? w2[0] : 0);
    cur[t] = excl;
    int node = (b << BSH) + t;
    if (node < N) row_ptr[node] = mb + excl;
  }
  if (b == 0 && t == 0) row_ptr[N] = E;
  __syncthreads();
  if (m <= CAP) {
    for (int i = t; i < m; i += 256) {
      int2 p = pairs[mb + i];
      int pos = atomicAdd(&cur[p.y & 127], 1);
      cl[pos] = p.x;
    }
    __syncthreads();
    for (int i = t; i < m; i += 256) col[mb + i] = cl[i];
  } else {  // overflow fallback (never hit for this input)
    for (int i = t; i < m; i += 256) {
      int2 p = pairs[mb + i];
      int pos = atomicAdd(&cur[p.y & 127], 1);
      col[mb + pos] = p.x;
    }
  }
}

// ---------------- weight prep: Wcat^T in f16 hi/lo, scaled ----------------
__global__ void prep_kernel(const float* __restrict__ Wrel, const float* __restrict__ Wroot,
                            _Float16* __restrict__ Whi, _Float16* __restrict__ Wlo,
                            float wscale) {
  int idx = blockIdx.x * blockDim.x + threadIdx.x;  // col*256 + k
  int col = idx >> 8;
  int k = idx & 255;
  float v = (k < 128) ? Wrel[k * 128 + col] : Wroot[(k - 128) * 128 + col];
  v *= wscale;
  _Float16 hi = (_Float16)v;
  _Float16 lo = (_Float16)(v - (float)hi);
  Whi[idx] = hi;
  Wlo[idx] = lo;
}

// ---------------- fused gather + GEMM ----------------
// out = relu(concat[sum_{nbr} h, h] @ Wcat + b*bscale), fp16 in/out
__global__ __launch_bounds__(256) void gemm_fused(const _Float16* __restrict__ hin,
                                                  const int* __restrict__ row_ptr,
                                                  const int* __restrict__ col,
                                                  const _Float16* __restrict__ Whi,
                                                  const _Float16* __restrict__ Wlo,
                                                  const float* __restrict__ bias,
                                                  float bscale,
                                                  _Float16* __restrict__ out, int N) {
  __shared__ unsigned lds[64 * 64];  // agg tile [64 rows][64 u32], XOR-swizzled
  const unsigned* __restrict__ h2 = (const unsigned*)hin;
  int t = threadIdx.x, w = t >> 6, lane = t & 63;
  int row_base = blockIdx.x * 64;

  // ---- gather phase: wave w accumulates rows w*16..w*16+15 ----
  for (int rr = 0; rr < 16; ++rr) {
    int row = row_base + w * 16 + rr;
    float ax = 0.f, ay = 0.f;
    if (row < N) {
      int s = __builtin_amdgcn_readfirstlane(row_ptr[row]);
      int e = __builtin_amdgcn_readfirstlane(row_ptr[row + 1]);
      int i = s;
      for (; i + 7 < e; i += 8) {
        unsigned v0 = h2[(size_t)col[i + 0] * 64 + lane];
        unsigned v1 = h2[(size_t)col[i + 1] * 64 + lane];
        unsigned v2 = h2[(size_t)col[i + 2] * 64 + lane];
        unsigned v3 = h2[(size_t)col[i + 3] * 64 + lane];
        unsigned v4 = h2[(size_t)col[i + 4] * 64 + lane];
        unsigned v5 = h2[(size_t)col[i + 5] * 64 + lane];
        unsigned v6 = h2[(size_t)col[i + 6] * 64 + lane];
        unsigned v7 = h2[(size_t)col[i + 7] * 64 + lane];
        float2 f0 = h2f2(v0), f1 = h2f2(v1), f2 = h2f2(v2), f3 = h2f2(v3);
        float2 f4 = h2f2(v4), f5 = h2f2(v5), f6 = h2f2(v6), f7 = h2f2(v7);
        ax += (f0.x + f1.x) + (f2.x + f3.x) + ((f4.x + f5.x) + (f6.x + f7.x));
        ay += (f0.y + f1.y) + (f2.y + f3.y) + ((f4.y + f5.y) + (f6.y + f7.y));
      }
      for (; i < e; ++i) {
        float2 f0 = h2f2(h2[(size_t)col[i] * 64 + lane]);
        ax += f0.x; ay += f0.y;
      }
    }
    int rl = w * 16 + rr;
    unsigned byte = (unsigned)(rl * 256 + lane * 4) ^ (unsigned)((rl & 7) << 4);
    lds[byte >> 2] = f2h2(ax, ay);
  }
  __syncthreads();

  // ---- MFMA phase ----
  int wv = w;
  int l16 = lane & 15;
  int khalf = lane >> 4;
  int koff = khalf * 8;
  int col_base = wv * 32;

  f32x4 acc[4][2];
  #pragma unroll
  for (int r = 0; r < 4; r++)
    #pragma unroll
    for (int c = 0; c < 2; c++) acc[r][c] = (f32x4){0.f, 0.f, 0.f, 0.f};

  #pragma unroll
  for (int ks = 0; ks < 8; ++ks) {
    int k0 = ks * 32;
    f16x8 bh[2], bl[2];
    #pragma unroll
    for (int c = 0; c < 2; c++) {
      int cc = col_base + c * 16 + l16;
      bh[c] = *(const f16x8*)(Whi + cc * 256 + k0 + koff);
      bl[c] = *(const f16x8*)(Wlo + cc * 256 + k0 + koff);
    }
    #pragma unroll
    for (int r = 0; r < 4; r++) {
      f16x8 a;
      if (ks < 4) {
        int arow = r * 16 + l16;
        unsigned byte = (unsigned)(arow * 256 + (k0 + koff) * 2) ^ (unsigned)((arow & 7) << 4);
        a = *(const f16x8*)((const char*)lds + byte);
      } else {
        int row = row_base + r * 16 + l16;
        if (row >= N) row = N - 1;
        a = *(const f16x8*)(hin + (size_t)row * 128 + (k0 - 128) + koff);
      }
      #pragma unroll
      for (int c = 0; c < 2; c++) {
        acc[r][c] = __builtin_amdgcn_mfma_f32_16x16x32_f16(a, bh[c], acc[r][c], 0, 0, 0);
        acc[r][c] = __builtin_amdgcn_mfma_f32_16x16x32_f16(a, bl[c], acc[r][c], 0, 0, 0);
      }
    }
  }

  #pragma unroll
  for (int r = 0; r < 4; r++) {
    #pragma unroll
    for (int c = 0; c < 2; c++) {
      int cc = col_base + c * 16 + l16;
      float b = bias[cc] * bscale;
      #pragma unroll
      for (int tt = 0; tt < 4; tt++) {
        int row = row_base + r * 16 + khalf * 4 + tt;
        if (row < N) {
          float v = acc[r][c][tt] + b;
          out[(size_t)row * 128 + cc] = (_Float16)(v > 0.f ? v : 0.f);
        }
      }
    }
  }
}

// ---------------- fused pool + MLP head (batch sorted) ----------------
static __device__ __forceinline__ int lbound(const int* __restrict__ a, int n, int v) {
  int lo = 0, hi = n;
  while (lo < hi) {
    int m = (lo + hi) >> 1;
    if (a[m] < v) lo = m + 1; else hi = m;
  }
  return lo;
}

__global__ __launch_bounds__(128) void poolhead_kernel(const _Float16* __restrict__ h,
                                                       const int* __restrict__ batch,
                                                       const float* __restrict__ fc1W,
                                                       const float* __restrict__ fc1b,
                                                       const float* __restrict__ fc2W,
                                                       const float* __restrict__ fc2b,
                                                       float* __restrict__ out, int N,
                                                       float unscale) {
  int gid = blockIdx.x, j = threadIdx.x;
  int start = lbound(batch, N, gid);
  int end = lbound(batch, N, gid + 1);
  float acc = 0.f;
  int r = start;
  for (; r + 3 < end; r += 4) {
    acc += (float)h[(size_t)r * 128 + j] + (float)h[(size_t)(r + 1) * 128 + j] +
           (float)h[(size_t)(r + 2) * 128 + j] + (float)h[(size_t)(r + 3) * 128 + j];
  }
  for (; r < end; ++r) acc += (float)h[(size_t)r * 128 + j];
  __shared__ float grow[128];
  __shared__ float red[128];
  grow[j] = acc * unscale;
  __syncthreads();
  float a1 = fc1b[j];
  #pragma unroll 8
  for (int k = 0; k < 128; ++k) a1 = fmaf(grow[k], fc1W[k * 128 + j], a1);
  a1 = a1 > 0.f ? a1 : 0.f;
  red[j] = a1 * fc2W[j];
  __syncthreads();
  #pragma unroll
  for (int s2 = 64; s2 > 0; s2 >>= 1) {
    if (j < s2) red[j] += red[j + s2];
    __syncthreads();
  }
  if (j == 0) out[gid] = red[0] + fc2b[0];
}

extern "C" void kernel_launch(void* const* d_in, const int* in_sizes, int n_in,
                              void* d_out, int out_size, void* d_ws, size_t ws_size,
                              hipStream_t stream) {
  const float* x = (const float*)d_in[0];
  const int* edge = (const int*)d_in[1];
  const int* batch = (const int*)d_in[2];
  const int N = in_sizes[0] / 128;
  const int E = in_sizes[1] / 2;
  const int G = out_size;
  const int* esrc = edge;
  const int* edst = edge + E;
  const int NB = (N + 127) >> BSH;  // buckets

  char* ws = (char*)d_ws;
  size_t off = 0;
  auto alloc = [&](size_t bytes) -> void* {
    void* p = ws + off;
    off = (off + bytes + 255) & ~(size_t)255;
    return p;
  };
  _Float16* x16  = (_Float16*)alloc((size_t)N * 128 * 2);
  _Float16* bufA = (_Float16*)alloc((size_t)N * 128 * 2);
  _Float16* bufB = (_Float16*)alloc((size_t)N * 128 * 2);
  _Float16* Whi  = (_Float16*)alloc((size_t)5 * 32768 * 2);
  _Float16* Wlo  = (_Float16*)alloc((size_t)5 * 32768 * 2);
  int* row_ptr   = (int*)alloc((size_t)(N + 1) * 4);
  int* col       = (int*)alloc((size_t)E * 4);
  int2* pairs    = (int2*)alloc((size_t)E * 8);
  int* gcnt      = (int*)alloc(512 * 4);
  int* base      = (int*)alloc(520 * 4);
  int* gcursor   = (int*)alloc(512 * 4);
  if (off > ws_size) return;  // fail loudly

  hipMemsetAsync(gcnt, 0, 512 * 4, stream);

  int nb1 = (E + CHUNK - 1) / CHUNK;
  bhist_kernel<<<nb1, 256, 0, stream>>>(edst, gcnt, E, NB);
  bscan_kernel<<<1, 512, 0, stream>>>(gcnt, base, gcursor, NB, E);
  bscatter_kernel<<<nb1, 256, 0, stream>>>(esrc, edst, gcursor, pairs, E, NB);
  bbuild_kernel<<<NB, 256, 0, stream>>>(pairs, base, row_ptr, col, N, E);

  cvt_kernel<<<(N * 128 / 4 + 255) / 256, 256, 0, stream>>>(x, x16, N * 128 / 4);

  // h'_l = h_l / 8^l keeps fp16 in range; weights *1/8, bias *8^-(l+1), undone at pool.
  const float S = 8.0f;
  float bscale = 1.0f;
  for (int l = 0; l < 5; ++l) {
    prep_kernel<<<128, 256, 0, stream>>>((const float*)d_in[4 + 3 * l],
                                         (const float*)d_in[6 + 3 * l],
                                         Whi + (size_t)l * 32768, Wlo + (size_t)l * 32768,
                                         1.0f / S);
  }

  const _Float16* hin = x16;
  _Float16* hout = bufA;
  int gemm_grid = (N + 63) / 64;
  for (int l = 0; l < 5; ++l) {
    bscale /= S;
    gemm_fused<<<gemm_grid, 256, 0, stream>>>(hin, row_ptr, col,
                                              Whi + (size_t)l * 32768, Wlo + (size_t)l * 32768,
                                              (const float*)d_in[5 + 3 * l], bscale, hout, N);
    hin = hout;
    hout = (hout == bufA) ? bufB : bufA;
  }
  poolhead_kernel<<<G, 128, 0, stream>>>(hin, batch,
                                         (const float*)d_in[19], (const float*)d_in[20],
                                         (const float*)d_in[21], (const float*)d_in[22],
                                         (float*)d_out, N, 32768.0f);
}

// Round 5
// 408.832 us; speedup vs baseline: 1.8308x; 1.0312x over previous
//
#include <hip/hip_runtime.h>
#include <hip/hip_bf16.h>

typedef __attribute__((ext_vector_type(4))) float f32x4;
typedef __attribute__((ext_vector_type(8))) _Float16 f16x8;
typedef __attribute__((ext_vector_type(4))) _Float16 f16x4;

#define CHUNK 4096   // edges per pass-1 block
#define BSH 7        // nodes per bucket = 128
#define CAP 4096     // max edges per bucket handled in LDS fast path
#define TM 32        // rows per gemm block

static __device__ __forceinline__ unsigned f2h2(float x, float y) {
  unsigned short lo = __builtin_bit_cast(unsigned short, (_Float16)x);
  unsigned short hi = __builtin_bit_cast(unsigned short, (_Float16)y);
  return ((unsigned)hi << 16) | lo;
}

// ---------------- fp32 -> fp16 convert ----------------
__global__ __launch_bounds__(256) void cvt_kernel(const float* __restrict__ x,
                                                  _Float16* __restrict__ h, int total4) {
  int i = blockIdx.x * blockDim.x + threadIdx.x;
  if (i < total4) {
    float4 v = *(const float4*)(x + (size_t)i * 4);
    f16x4 o = {(_Float16)v.x, (_Float16)v.y, (_Float16)v.z, (_Float16)v.w};
    *(f16x4*)(h + (size_t)i * 4) = o;
  }
}

// ---------------- CSR build: bucketed counting sort ----------------
__global__ __launch_bounds__(256) void bhist_kernel(const int* __restrict__ dst,
                                                    int* __restrict__ gcnt, int E, int nb) {
  __shared__ int l[512];
  int t = threadIdx.x;
  for (int i = t; i < 512; i += 256) l[i] = 0;
  __syncthreads();
  int cbase = blockIdx.x * CHUNK;
  #pragma unroll
  for (int i = 0; i < CHUNK / 256; ++i) {
    int idx = cbase + i * 256 + t;
    if (idx < E) atomicAdd(&l[dst[idx] >> BSH], 1);
  }
  __syncthreads();
  for (int i = t; i < nb; i += 256) {
    int c = l[i];
    if (c) atomicAdd(&gcnt[i], c);
  }
}

__global__ __launch_bounds__(512) void bscan_kernel(const int* __restrict__ gcnt,
                                                    int* __restrict__ base,
                                                    int* __restrict__ gcursor, int nb, int E) {
  __shared__ int wsum[8], wpre[8];
  int t = threadIdx.x, lane = t & 63, w = t >> 6;
  int v = (t < nb) ? gcnt[t] : 0;
  int incl = v;
  #pragma unroll
  for (int o = 1; o < 64; o <<= 1) {
    int x = __shfl_up(incl, o, 64);
    if (lane >= o) incl += x;
  }
  if (lane == 63) wsum[w] = incl;
  __syncthreads();
  if (t == 0) {
    int run = 0;
    #pragma unroll
    for (int q = 0; q < 8; ++q) { wpre[q] = run; run += wsum[q]; }
  }
  __syncthreads();
  int excl = wpre[w] + incl - v;
  if (t < nb) { base[t] = excl; gcursor[t] = excl; }
  if (t == 0) base[nb] = E;
}

__global__ __launch_bounds__(256) void bscatter_kernel(const int* __restrict__ src,
                                                       const int* __restrict__ dst,
                                                       int* __restrict__ gcursor,
                                                       int2* __restrict__ pairs, int E, int nb) {
  __shared__ int lcnt[512], lstart[512], lpos[512], lgbase[512];
  __shared__ int2 lp[CHUNK];
  __shared__ int wsum[4], wpre[4];
  int t = threadIdx.x, lane = t & 63, w = t >> 6;
  for (int i = t; i < 512; i += 256) lcnt[i] = 0;
  __syncthreads();
  int cbase = blockIdx.x * CHUNK;
  int m = E - cbase; if (m > CHUNK) m = CHUNK;
  #pragma unroll
  for (int i = 0; i < CHUNK / 256; ++i) {
    int idx = i * 256 + t;
    if (idx < m) atomicAdd(&lcnt[dst[cbase + idx] >> BSH], 1);
  }
  __syncthreads();
  int c0 = lcnt[2 * t], c1 = lcnt[2 * t + 1];
  int s = c0 + c1, incl = s;
  #pragma unroll
  for (int o = 1; o < 64; o <<= 1) {
    int x = __shfl_up(incl, o, 64);
    if (lane >= o) incl += x;
  }
  if (lane == 63) wsum[w] = incl;
  __syncthreads();
  if (t == 0) {
    int run = 0;
    #pragma unroll
    for (int q = 0; q < 4; ++q) { wpre[q] = run; run += wsum[q]; }
  }
  __syncthreads();
  int excl = wpre[w] + incl - s;
  lstart[2 * t] = excl;          lpos[2 * t] = excl;
  lstart[2 * t + 1] = excl + c0; lpos[2 * t + 1] = excl + c0;
  if (2 * t < nb && c0 > 0) lgbase[2 * t] = atomicAdd(&gcursor[2 * t], c0);
  if (2 * t + 1 < nb && c1 > 0) lgbase[2 * t + 1] = atomicAdd(&gcursor[2 * t + 1], c1);
  __syncthreads();
  #pragma unroll
  for (int i = 0; i < CHUNK / 256; ++i) {
    int idx = i * 256 + t;
    if (idx < m) {
      int d = dst[cbase + idx], sv = src[cbase + idx];
      int p = atomicAdd(&lpos[d >> BSH], 1);
      lp[p] = make_int2(sv, d);
    }
  }
  __syncthreads();
  for (int i = t; i < m; i += 256) {
    int2 pr = lp[i];
    int b = pr.y >> BSH;
    pairs[lgbase[b] + (i - lstart[b])] = pr;
  }
}

__global__ __launch_bounds__(256) void bbuild_kernel(const int2* __restrict__ pairs,
                                                     const int* __restrict__ base,
                                                     int* __restrict__ row_ptr,
                                                     int* __restrict__ col, int N, int E) {
  __shared__ int cnt[128], cur[128], w2[2];
  __shared__ int cl[CAP];
  int b = blockIdx.x, t = threadIdx.x;
  int mb = base[b], me = base[b + 1], m = me - mb;
  if (t < 128) cnt[t] = 0;
  __syncthreads();
  for (int i = t; i < m; i += 256) atomicAdd(&cnt[pairs[mb + i].y & 127], 1);
  __syncthreads();
  int v = 0, incl = 0;
  if (t < 128) {
    v = cnt[t]; incl = v;
    #pragma unroll
    for (int o = 1; o < 64; o <<= 1) {
      int x = __shfl_up(incl, o, 64);
      if ((t & 63) >= o) incl += x;
    }
    if ((t & 63) == 63) w2[t >> 6] = incl;
  }
  __syncthreads();
  if (t < 128) {
    int excl = incl - v + ((t & 64) ? w2[0] : 0);
    cur[t] = excl;
    int node = (b << BSH) + t;
    if (node < N) row_ptr[node] = mb + excl;
  }
  if (b == 0 && t == 0) row_ptr[N] = E;
  __syncthreads();
  if (m <= CAP) {
    for (int i = t; i < m; i += 256) {
      int2 p = pairs[mb + i];
      int pos = atomicAdd(&cur[p.y & 127], 1);
      cl[pos] = p.x;
    }
    __syncthreads();
    for (int i = t; i < m; i += 256) col[mb + i] = cl[i];
  } else {
    for (int i = t; i < m; i += 256) {
      int2 p = pairs[mb + i];
      int pos = atomicAdd(&cur[p.y & 127], 1);
      col[mb + pos] = p.x;
    }
  }
}

// ---------------- weight prep: Wcat^T in f16 hi/lo, scaled ----------------
__global__ void prep_kernel(const float* __restrict__ Wrel, const float* __restrict__ Wroot,
                            _Float16* __restrict__ Whi, _Float16* __restrict__ Wlo,
                            float wscale) {
  int idx = blockIdx.x * blockDim.x + threadIdx.x;  // col*256 + k
  int col = idx >> 8;
  int k = idx & 255;
  float v = (k < 128) ? Wrel[k * 128 + col] : Wroot[(k - 128) * 128 + col];
  v *= wscale;
  _Float16 hi = (_Float16)v;
  _Float16 lo = (_Float16)(v - (float)hi);
  Whi[idx] = hi;
  Wlo[idx] = lo;
}

// ---------------- fused gather + GEMM, 32-row tile ----------------
// out = relu(concat[sum_{nbr} h, h] @ Wcat + b*bscale), fp16 in/out
__global__ __launch_bounds__(256) void gemm_fused(const _Float16* __restrict__ hin,
                                                  const int* __restrict__ row_ptr,
                                                  const int* __restrict__ col,
                                                  const _Float16* __restrict__ Whi,
                                                  const _Float16* __restrict__ Wlo,
                                                  const float* __restrict__ bias,
                                                  float bscale,
                                                  _Float16* __restrict__ out, int N) {
  __shared__ unsigned lds[TM * 64];  // agg tile [32 rows][64 u32], XOR-swizzled
  const f16x8* __restrict__ hp = (const f16x8*)hin;
  int t = threadIdx.x, w = t >> 6, lane = t & 63;
  int g = lane >> 4, l16 = lane & 15;
  int row_base = blockIdx.x * TM;

  // ---- gather: each wave runs 4 rows in parallel (16-lane groups), 2 chunks ----
  #pragma unroll
  for (int chunk = 0; chunk < 2; ++chunk) {
    int rl = w * 8 + chunk * 4 + g;  // local row 0..31
    int row = row_base + rl;
    float acc[8];
    #pragma unroll
    for (int q = 0; q < 8; ++q) acc[q] = 0.f;
    if (row < N) {
      int s = row_ptr[row], e = row_ptr[row + 1];
      int i = s;
      for (; i + 3 < e; i += 4) {
        int c0 = col[i], c1 = col[i + 1], c2 = col[i + 2], c3 = col[i + 3];
        f16x8 v0 = hp[(size_t)c0 * 16 + l16];
        f16x8 v1 = hp[(size_t)c1 * 16 + l16];
        f16x8 v2 = hp[(size_t)c2 * 16 + l16];
        f16x8 v3 = hp[(size_t)c3 * 16 + l16];
        #pragma unroll
        for (int q = 0; q < 8; ++q)
          acc[q] += ((float)v0[q] + (float)v1[q]) + ((float)v2[q] + (float)v3[q]);
      }
      for (; i < e; ++i) {
        f16x8 v0 = hp[(size_t)col[i] * 16 + l16];
        #pragma unroll
        for (int q = 0; q < 8; ++q) acc[q] += (float)v0[q];
      }
    }
    f16x8 o;
    #pragma unroll
    for (int q = 0; q < 8; ++q) o[q] = (_Float16)acc[q];
    unsigned byte = (unsigned)(rl * 256 + l16 * 16) ^ (unsigned)((rl & 7) << 4);
    *(f16x8*)((char*)lds + byte) = o;
  }
  __syncthreads();

  // ---- MFMA phase: 32 rows x 128 cols; wave w owns cols w*32..+32 ----
  int khalf = lane >> 4;  // 0..3
  int koff = khalf * 8;
  int col_base = w * 32;

  f32x4 acc[2][2];
  #pragma unroll
  for (int r = 0; r < 2; r++)
    #pragma unroll
    for (int c = 0; c < 2; c++) acc[r][c] = (f32x4){0.f, 0.f, 0.f, 0.f};

  #pragma unroll
  for (int ks = 0; ks < 8; ++ks) {
    int k0 = ks * 32;
    f16x8 bh[2], bl[2];
    #pragma unroll
    for (int c = 0; c < 2; c++) {
      int cc = col_base + c * 16 + l16;
      bh[c] = *(const f16x8*)(Whi + cc * 256 + k0 + koff);
      bl[c] = *(const f16x8*)(Wlo + cc * 256 + k0 + koff);
    }
    #pragma unroll
    for (int r = 0; r < 2; r++) {
      f16x8 a;
      if (ks < 4) {
        int arow = r * 16 + l16;
        unsigned byte = (unsigned)(arow * 256 + k0 * 2 + khalf * 16) ^ (unsigned)((arow & 7) << 4);
        a = *(const f16x8*)((const char*)lds + byte);
      } else {
        int row = row_base + r * 16 + l16;
        if (row >= N) row = N - 1;
        a = *(const f16x8*)(hin + (size_t)row * 128 + (k0 - 128) + koff);
      }
      #pragma unroll
      for (int c = 0; c < 2; c++) {
        acc[r][c] = __builtin_amdgcn_mfma_f32_16x16x32_f16(a, bh[c], acc[r][c], 0, 0, 0);
        acc[r][c] = __builtin_amdgcn_mfma_f32_16x16x32_f16(a, bl[c], acc[r][c], 0, 0, 0);
      }
    }
  }

  #pragma unroll
  for (int r = 0; r < 2; r++) {
    #pragma unroll
    for (int c = 0; c < 2; c++) {
      int cc = col_base + c * 16 + l16;
      float b = bias[cc] * bscale;
      #pragma unroll
      for (int tt = 0; tt < 4; tt++) {
        int row = row_base + r * 16 + khalf * 4 + tt;
        if (row < N) {
          float v = acc[r][c][tt] + b;
          out[(size_t)row * 128 + cc] = (_Float16)(v > 0.f ? v : 0.f);
        }
      }
    }
  }
}

// ---------------- fused pool + MLP head (batch sorted) ----------------
static __device__ __forceinline__ int lbound(const int* __restrict__ a, int n, int v) {
  int lo = 0, hi = n;
  while (lo < hi) {
    int m = (lo + hi) >> 1;
    if (a[m] < v) lo = m + 1; else hi = m;
  }
  return lo;
}

__global__ __launch_bounds__(128) void poolhead_kernel(const _Float16* __restrict__ h,
                                                       const int* __restrict__ batch,
                                                       const float* __restrict__ fc1W,
                                                       const float* __restrict__ fc1b,
                                                       const float* __restrict__ fc2W,
                                                       const float* __restrict__ fc2b,
                                                       float* __restrict__ out, int N,
                                                       float unscale) {
  int gid = blockIdx.x, j = threadIdx.x;
  int start = lbound(batch, N, gid);
  int end = lbound(batch, N, gid + 1);
  float acc = 0.f;
  int r = start;
  for (; r + 3 < end; r += 4) {
    acc += (float)h[(size_t)r * 128 + j] + (float)h[(size_t)(r + 1) * 128 + j] +
           (float)h[(size_t)(r + 2) * 128 + j] + (float)h[(size_t)(r + 3) * 128 + j];
  }
  for (; r < end; ++r) acc += (float)h[(size_t)r * 128 + j];
  __shared__ float grow[128];
  __shared__ float red[128];
  grow[j] = acc * unscale;
  __syncthreads();
  float a1 = fc1b[j];
  #pragma unroll 8
  for (int k = 0; k < 128; ++k) a1 = fmaf(grow[k], fc1W[k * 128 + j], a1);
  a1 = a1 > 0.f ? a1 : 0.f;
  red[j] = a1 * fc2W[j];
  __syncthreads();
  #pragma unroll
  for (int s2 = 64; s2 > 0; s2 >>= 1) {
    if (j < s2) red[j] += red[j + s2];
    __syncthreads();
  }
  if (j == 0) out[gid] = red[0] + fc2b[0];
}

extern "C" void kernel_launch(void* const* d_in, const int* in_sizes, int n_in,
                              void* d_out, int out_size, void* d_ws, size_t ws_size,
                              hipStream_t stream) {
  const float* x = (const float*)d_in[0];
  const int* edge = (const int*)d_in[1];
  const int* batch = (const int*)d_in[2];
  const int N = in_sizes[0] / 128;
  const int E = in_sizes[1] / 2;
  const int G = out_size;
  const int* esrc = edge;
  const int* edst = edge + E;
  const int NB = (N + 127) >> BSH;  // buckets

  char* ws = (char*)d_ws;
  size_t off = 0;
  auto alloc = [&](size_t bytes) -> void* {
    void* p = ws + off;
    off = (off + bytes + 255) & ~(size_t)255;
    return p;
  };
  _Float16* x16  = (_Float16*)alloc((size_t)N * 128 * 2);
  _Float16* bufA = (_Float16*)alloc((size_t)N * 128 * 2);
  _Float16* bufB = (_Float16*)alloc((size_t)N * 128 * 2);
  _Float16* Whi  = (_Float16*)alloc((size_t)5 * 32768 * 2);
  _Float16* Wlo  = (_Float16*)alloc((size_t)5 * 32768 * 2);
  int* row_ptr   = (int*)alloc((size_t)(N + 1) * 4);
  int* col       = (int*)alloc((size_t)E * 4);
  int2* pairs    = (int2*)alloc((size_t)E * 8);
  int* gcnt      = (int*)alloc(512 * 4);
  int* base      = (int*)alloc(520 * 4);
  int* gcursor   = (int*)alloc(512 * 4);
  if (off > ws_size) return;  // fail loudly

  hipMemsetAsync(gcnt, 0, 512 * 4, stream);

  int nb1 = (E + CHUNK - 1) / CHUNK;
  bhist_kernel<<<nb1, 256, 0, stream>>>(edst, gcnt, E, NB);
  bscan_kernel<<<1, 512, 0, stream>>>(gcnt, base, gcursor, NB, E);
  bscatter_kernel<<<nb1, 256, 0, stream>>>(esrc, edst, gcursor, pairs, E, NB);
  bbuild_kernel<<<NB, 256, 0, stream>>>(pairs, base, row_ptr, col, N, E);

  cvt_kernel<<<(N * 128 / 4 + 255) / 256, 256, 0, stream>>>(x, x16, N * 128 / 4);

  // h'_l = h_l / 8^l keeps fp16 in range; weights *1/8, bias *8^-(l+1), undone at pool.
  const float S = 8.0f;
  float bscale = 1.0f;
  for (int l = 0; l < 5; ++l) {
    prep_kernel<<<128, 256, 0, stream>>>((const float*)d_in[4 + 3 * l],
                                         (const float*)d_in[6 + 3 * l],
                                         Whi + (size_t)l * 32768, Wlo + (size_t)l * 32768,
                                         1.0f / S);
  }

  const _Float16* hin = x16;
  _Float16* hout = bufA;
  int gemm_grid = (N + TM - 1) / TM;
  for (int l = 0; l < 5; ++l) {
    bscale /= S;
    gemm_fused<<<gemm_grid, 256, 0, stream>>>(hin, row_ptr, col,
                                              Whi + (size_t)l * 32768, Wlo + (size_t)l * 32768,
                                              (const float*)d_in[5 + 3 * l], bscale, hout, N);
    hin = hout;
    hout = (hout == bufA) ? bufB : bufA;
  }
  poolhead_kernel<<<G, 128, 0, stream>>>(hin, batch,
                                         (const float*)d_in[19], (const float*)d_in[20],
                                         (const float*)d_in[21], (const float*)d_in[22],
                                         (float*)d_out, N, 32768.0f);
}

// Round 6
// 383.398 us; speedup vs baseline: 1.9523x; 1.0663x over previous
//
#include <hip/hip_runtime.h>
#include <hip/hip_bf16.h>

typedef __attribute__((ext_vector_type(4))) float f32x4;
typedef __attribute__((ext_vector_type(8))) _Float16 f16x8;
typedef __attribute__((ext_vector_type(4))) _Float16 f16x4;

#define CHUNK 4096   // edges per pass-1 block
#define BSH 7        // nodes per bucket = 128
#define CAP 4096     // max edges per bucket handled in LDS fast path
#define TM 32        // rows per gemm block

// ---------------- fp32 -> fp16 convert ----------------
__global__ __launch_bounds__(256) void cvt_kernel(const float* __restrict__ x,
                                                  _Float16* __restrict__ h, int total4) {
  int i = blockIdx.x * blockDim.x + threadIdx.x;
  if (i < total4) {
    float4 v = *(const float4*)(x + (size_t)i * 4);
    f16x4 o = {(_Float16)v.x, (_Float16)v.y, (_Float16)v.z, (_Float16)v.w};
    *(f16x4*)(h + (size_t)i * 4) = o;
  }
}

// ---------------- CSR build: bucketed counting sort ----------------
__global__ __launch_bounds__(256) void bhist_kernel(const int* __restrict__ dst,
                                                    int* __restrict__ gcnt, int E, int nb) {
  __shared__ int l[512];
  int t = threadIdx.x;
  for (int i = t; i < 512; i += 256) l[i] = 0;
  __syncthreads();
  int cbase = blockIdx.x * CHUNK;
  #pragma unroll
  for (int i = 0; i < CHUNK / 256; ++i) {
    int idx = cbase + i * 256 + t;
    if (idx < E) atomicAdd(&l[dst[idx] >> BSH], 1);
  }
  __syncthreads();
  for (int i = t; i < nb; i += 256) {
    int c = l[i];
    if (c) atomicAdd(&gcnt[i], c);
  }
}

__global__ __launch_bounds__(512) void bscan_kernel(const int* __restrict__ gcnt,
                                                    int* __restrict__ base,
                                                    int* __restrict__ gcursor, int nb, int E) {
  __shared__ int wsum[8], wpre[8];
  int t = threadIdx.x, lane = t & 63, w = t >> 6;
  int v = (t < nb) ? gcnt[t] : 0;
  int incl = v;
  #pragma unroll
  for (int o = 1; o < 64; o <<= 1) {
    int x = __shfl_up(incl, o, 64);
    if (lane >= o) incl += x;
  }
  if (lane == 63) wsum[w] = incl;
  __syncthreads();
  if (t == 0) {
    int run = 0;
    #pragma unroll
    for (int q = 0; q < 8; ++q) { wpre[q] = run; run += wsum[q]; }
  }
  __syncthreads();
  int excl = wpre[w] + incl - v;
  if (t < nb) { base[t] = excl; gcursor[t] = excl; }
  if (t == 0) base[nb] = E;
}

__global__ __launch_bounds__(256) void bscatter_kernel(const int* __restrict__ src,
                                                       const int* __restrict__ dst,
                                                       int* __restrict__ gcursor,
                                                       int2* __restrict__ pairs, int E, int nb) {
  __shared__ int lcnt[512], lstart[512], lpos[512], lgbase[512];
  __shared__ int2 lp[CHUNK];
  __shared__ int wsum[4], wpre[4];
  int t = threadIdx.x, lane = t & 63, w = t >> 6;
  for (int i = t; i < 512; i += 256) lcnt[i] = 0;
  __syncthreads();
  int cbase = blockIdx.x * CHUNK;
  int m = E - cbase; if (m > CHUNK) m = CHUNK;
  #pragma unroll
  for (int i = 0; i < CHUNK / 256; ++i) {
    int idx = i * 256 + t;
    if (idx < m) atomicAdd(&lcnt[dst[cbase + idx] >> BSH], 1);
  }
  __syncthreads();
  int c0 = lcnt[2 * t], c1 = lcnt[2 * t + 1];
  int s = c0 + c1, incl = s;
  #pragma unroll
  for (int o = 1; o < 64; o <<= 1) {
    int x = __shfl_up(incl, o, 64);
    if (lane >= o) incl += x;
  }
  if (lane == 63) wsum[w] = incl;
  __syncthreads();
  if (t == 0) {
    int run = 0;
    #pragma unroll
    for (int q = 0; q < 4; ++q) { wpre[q] = run; run += wsum[q]; }
  }
  __syncthreads();
  int excl = wpre[w] + incl - s;
  lstart[2 * t] = excl;          lpos[2 * t] = excl;
  lstart[2 * t + 1] = excl + c0; lpos[2 * t + 1] = excl + c0;
  if (2 * t < nb && c0 > 0) lgbase[2 * t] = atomicAdd(&gcursor[2 * t], c0);
  if (2 * t + 1 < nb && c1 > 0) lgbase[2 * t + 1] = atomicAdd(&gcursor[2 * t + 1], c1);
  __syncthreads();
  #pragma unroll
  for (int i = 0; i < CHUNK / 256; ++i) {
    int idx = i * 256 + t;
    if (idx < m) {
      int d = dst[cbase + idx], sv = src[cbase + idx];
      int p = atomicAdd(&lpos[d >> BSH], 1);
      lp[p] = make_int2(sv, d);
    }
  }
  __syncthreads();
  for (int i = t; i < m; i += 256) {
    int2 pr = lp[i];
    int b = pr.y >> BSH;
    pairs[lgbase[b] + (i - lstart[b])] = pr;
  }
}

__global__ __launch_bounds__(256) void bbuild_kernel(const int2* __restrict__ pairs,
                                                     const int* __restrict__ base,
                                                     int* __restrict__ row_ptr,
                                                     int* __restrict__ col, int N, int E) {
  __shared__ int cnt[128], cur[128], w2[2];
  __shared__ int cl[CAP];
  int b = blockIdx.x, t = threadIdx.x;
  int mb = base[b], me = base[b + 1], m = me - mb;
  if (t < 128) cnt[t] = 0;
  __syncthreads();
  for (int i = t; i < m; i += 256) atomicAdd(&cnt[pairs[mb + i].y & 127], 1);
  __syncthreads();
  int v = 0, incl = 0;
  if (t < 128) {
    v = cnt[t]; incl = v;
    #pragma unroll
    for (int o = 1; o < 64; o <<= 1) {
      int x = __shfl_up(incl, o, 64);
      if ((t & 63) >= o) incl += x;
    }
    if ((t & 63) == 63) w2[t >> 6] = incl;
  }
  __syncthreads();
  if (t < 128) {
    int excl = incl - v + ((t & 64) ? w2[0] : 0);
    cur[t] = excl;
    int node = (b << BSH) + t;
    if (node < N) row_ptr[node] = mb + excl;
  }
  if (b == 0 && t == 0) row_ptr[N] = E;
  __syncthreads();
  if (m <= CAP) {
    for (int i = t; i < m; i += 256) {
      int2 p = pairs[mb + i];
      int pos = atomicAdd(&cur[p.y & 127], 1);
      cl[pos] = p.x;
    }
    __syncthreads();
    for (int i = t; i < m; i += 256) col[mb + i] = cl[i];
  } else {
    for (int i = t; i < m; i += 256) {
      int2 p = pairs[mb + i];
      int pos = atomicAdd(&cur[p.y & 127], 1);
      col[mb + pos] = p.x;
    }
  }
}

// ---------------- weight prep: Wcat^T in f16 hi/lo, scaled ----------------
__global__ void prep_kernel(const float* __restrict__ Wrel, const float* __restrict__ Wroot,
                            _Float16* __restrict__ Whi, _Float16* __restrict__ Wlo,
                            float wscale) {
  int idx = blockIdx.x * blockDim.x + threadIdx.x;  // col*256 + k
  int col = idx >> 8;
  int k = idx & 255;
  float v = (k < 128) ? Wrel[k * 128 + col] : Wroot[(k - 128) * 128 + col];
  v *= wscale;
  _Float16 hi = (_Float16)v;
  _Float16 lo = (_Float16)(v - (float)hi);
  Whi[idx] = hi;
  Wlo[idx] = lo;
}

// ---------------- fused gather + GEMM, 32-row tile, pipelined gather ----------------
// out = relu(concat[sum_{nbr} h, h] @ Wcat + b*bscale), fp16 in/out
__global__ __launch_bounds__(256) void gemm_fused(const _Float16* __restrict__ hin,
                                                  const int* __restrict__ row_ptr,
                                                  const int* __restrict__ col,
                                                  const _Float16* __restrict__ Whi,
                                                  const _Float16* __restrict__ Wlo,
                                                  const float* __restrict__ bias,
                                                  float bscale,
                                                  _Float16* __restrict__ out, int N) {
  __shared__ unsigned lds[TM * 64];  // agg tile [32 rows][64 u32], XOR-swizzled
  const f16x8* __restrict__ hp = (const f16x8*)hin;
  int t = threadIdx.x, w = t >> 6, lane = t & 63;
  int g = lane >> 4, l16 = lane & 15;
  int row_base = blockIdx.x * TM;

  // ---- gather: each wave runs 4 rows in parallel (16-lane groups), 2 chunks ----
  // software-pipelined: col indices prefetched one 8-batch ahead; 8 gathers in flight
  #pragma unroll
  for (int chunk = 0; chunk < 2; ++chunk) {
    int rl = w * 8 + chunk * 4 + g;  // local row 0..31
    int row = row_base + rl;
    float acc[8];
    #pragma unroll
    for (int q = 0; q < 8; ++q) acc[q] = 0.f;
    if (row < N) {
      int s = row_ptr[row], e = row_ptr[row + 1];
      if (s < e) {
        int c[8];
        #pragma unroll
        for (int q = 0; q < 8; ++q) { int idx = s + q; c[q] = col[idx < e ? idx : e - 1]; }
        int i = s;
        for (; i + 8 <= e; i += 8) {
          f16x8 v[8];
          #pragma unroll
          for (int q = 0; q < 8; ++q) v[q] = hp[(size_t)c[q] * 16 + l16];
          #pragma unroll
          for (int q = 0; q < 8; ++q) { int idx = i + 8 + q; c[q] = col[idx < e ? idx : e - 1]; }
          #pragma unroll
          for (int z = 0; z < 8; ++z)
            acc[z] += (((float)v[0][z] + (float)v[1][z]) + ((float)v[2][z] + (float)v[3][z])) +
                      (((float)v[4][z] + (float)v[5][z]) + ((float)v[6][z] + (float)v[7][z]));
        }
        if (i < e) {  // masked final batch (c[] already holds clamped indices)
          f16x8 v[8];
          #pragma unroll
          for (int q = 0; q < 8; ++q) v[q] = hp[(size_t)c[q] * 16 + l16];
          #pragma unroll
          for (int q = 0; q < 8; ++q) {
            float m = (i + q < e) ? 1.f : 0.f;
            #pragma unroll
            for (int z = 0; z < 8; ++z) acc[z] = fmaf(m, (float)v[q][z], acc[z]);
          }
        }
      }
    }
    f16x8 o;
    #pragma unroll
    for (int q = 0; q < 8; ++q) o[q] = (_Float16)acc[q];
    unsigned byte = (unsigned)(rl * 256 + l16 * 16) ^ (unsigned)((rl & 7) << 4);
    *(f16x8*)((char*)lds + byte) = o;
  }
  __syncthreads();

  // ---- MFMA phase: 32 rows x 128 cols; wave w owns cols w*32..+32 ----
  int khalf = lane >> 4;  // 0..3
  int koff = khalf * 8;
  int col_base = w * 32;

  f32x4 acc[2][2];
  #pragma unroll
  for (int r = 0; r < 2; r++)
    #pragma unroll
    for (int c = 0; c < 2; c++) acc[r][c] = (f32x4){0.f, 0.f, 0.f, 0.f};

  #pragma unroll
  for (int ks = 0; ks < 8; ++ks) {
    int k0 = ks * 32;
    f16x8 bh[2], bl[2];
    #pragma unroll
    for (int c = 0; c < 2; c++) {
      int cc = col_base + c * 16 + l16;
      bh[c] = *(const f16x8*)(Whi + cc * 256 + k0 + koff);
      bl[c] = *(const f16x8*)(Wlo + cc * 256 + k0 + koff);
    }
    #pragma unroll
    for (int r = 0; r < 2; r++) {
      f16x8 a;
      if (ks < 4) {
        int arow = r * 16 + l16;
        unsigned byte = (unsigned)(arow * 256 + k0 * 2 + khalf * 16) ^ (unsigned)((arow & 7) << 4);
        a = *(const f16x8*)((const char*)lds + byte);
      } else {
        int row = row_base + r * 16 + l16;
        if (row >= N) row = N - 1;
        a = *(const f16x8*)(hin + (size_t)row * 128 + (k0 - 128) + koff);
      }
      #pragma unroll
      for (int c = 0; c < 2; c++) {
        acc[r][c] = __builtin_amdgcn_mfma_f32_16x16x32_f16(a, bh[c], acc[r][c], 0, 0, 0);
        acc[r][c] = __builtin_amdgcn_mfma_f32_16x16x32_f16(a, bl[c], acc[r][c], 0, 0, 0);
      }
    }
  }

  #pragma unroll
  for (int r = 0; r < 2; r++) {
    #pragma unroll
    for (int c = 0; c < 2; c++) {
      int cc = col_base + c * 16 + l16;
      float b = bias[cc] * bscale;
      #pragma unroll
      for (int tt = 0; tt < 4; tt++) {
        int row = row_base + r * 16 + khalf * 4 + tt;
        if (row < N) {
          float v = acc[r][c][tt] + b;
          out[(size_t)row * 128 + cc] = (_Float16)(v > 0.f ? v : 0.f);
        }
      }
    }
  }
}

// ---------------- fused pool + MLP head (batch sorted) ----------------
static __device__ __forceinline__ int lbound(const int* __restrict__ a, int n, int v) {
  int lo = 0, hi = n;
  while (lo < hi) {
    int m = (lo + hi) >> 1;
    if (a[m] < v) lo = m + 1; else hi = m;
  }
  return lo;
}

__global__ __launch_bounds__(128) void poolhead_kernel(const _Float16* __restrict__ h,
                                                       const int* __restrict__ batch,
                                                       const float* __restrict__ fc1W,
                                                       const float* __restrict__ fc1b,
                                                       const float* __restrict__ fc2W,
                                                       const float* __restrict__ fc2b,
                                                       float* __restrict__ out, int N,
                                                       float unscale) {
  int gid = blockIdx.x, j = threadIdx.x;
  int start = lbound(batch, N, gid);
  int end = lbound(batch, N, gid + 1);
  float acc = 0.f;
  int r = start;
  for (; r + 3 < end; r += 4) {
    acc += (float)h[(size_t)r * 128 + j] + (float)h[(size_t)(r + 1) * 128 + j] +
           (float)h[(size_t)(r + 2) * 128 + j] + (float)h[(size_t)(r + 3) * 128 + j];
  }
  for (; r < end; ++r) acc += (float)h[(size_t)r * 128 + j];
  __shared__ float grow[128];
  __shared__ float red[128];
  grow[j] = acc * unscale;
  __syncthreads();
  float a1 = fc1b[j];
  #pragma unroll 8
  for (int k = 0; k < 128; ++k) a1 = fmaf(grow[k], fc1W[k * 128 + j], a1);
  a1 = a1 > 0.f ? a1 : 0.f;
  red[j] = a1 * fc2W[j];
  __syncthreads();
  #pragma unroll
  for (int s2 = 64; s2 > 0; s2 >>= 1) {
    if (j < s2) red[j] += red[j + s2];
    __syncthreads();
  }
  if (j == 0) out[gid] = red[0] + fc2b[0];
}

extern "C" void kernel_launch(void* const* d_in, const int* in_sizes, int n_in,
                              void* d_out, int out_size, void* d_ws, size_t ws_size,
                              hipStream_t stream) {
  const float* x = (const float*)d_in[0];
  const int* edge = (const int*)d_in[1];
  const int* batch = (const int*)d_in[2];
  const int N = in_sizes[0] / 128;
  const int E = in_sizes[1] / 2;
  const int G = out_size;
  const int* esrc = edge;
  const int* edst = edge + E;
  const int NB = (N + 127) >> BSH;  // buckets

  char* ws = (char*)d_ws;
  size_t off = 0;
  auto alloc = [&](size_t bytes) -> void* {
    void* p = ws + off;
    off = (off + bytes + 255) & ~(size_t)255;
    return p;
  };
  _Float16* x16  = (_Float16*)alloc((size_t)N * 128 * 2);
  _Float16* bufA = (_Float16*)alloc((size_t)N * 128 * 2);
  _Float16* bufB = (_Float16*)alloc((size_t)N * 128 * 2);
  _Float16* Whi  = (_Float16*)alloc((size_t)5 * 32768 * 2);
  _Float16* Wlo  = (_Float16*)alloc((size_t)5 * 32768 * 2);
  int* row_ptr   = (int*)alloc((size_t)(N + 1) * 4);
  int* col       = (int*)alloc((size_t)E * 4);
  int2* pairs    = (int2*)alloc((size_t)E * 8);
  int* gcnt      = (int*)alloc(512 * 4);
  int* base      = (int*)alloc(520 * 4);
  int* gcursor   = (int*)alloc(512 * 4);
  if (off > ws_size) return;  // fail loudly

  hipMemsetAsync(gcnt, 0, 512 * 4, stream);

  int nb1 = (E + CHUNK - 1) / CHUNK;
  bhist_kernel<<<nb1, 256, 0, stream>>>(edst, gcnt, E, NB);
  bscan_kernel<<<1, 512, 0, stream>>>(gcnt, base, gcursor, NB, E);
  bscatter_kernel<<<nb1, 256, 0, stream>>>(esrc, edst, gcursor, pairs, E, NB);
  bbuild_kernel<<<NB, 256, 0, stream>>>(pairs, base, row_ptr, col, N, E);

  cvt_kernel<<<(N * 128 / 4 + 255) / 256, 256, 0, stream>>>(x, x16, N * 128 / 4);

  // h'_l = h_l / 8^l keeps fp16 in range; weights *1/8, bias *8^-(l+1), undone at pool.
  const float S = 8.0f;
  float bscale = 1.0f;
  for (int l = 0; l < 5; ++l) {
    prep_kernel<<<128, 256, 0, stream>>>((const float*)d_in[4 + 3 * l],
                                         (const float*)d_in[6 + 3 * l],
                                         Whi + (size_t)l * 32768, Wlo + (size_t)l * 32768,
                                         1.0f / S);
  }

  const _Float16* hin = x16;
  _Float16* hout = bufA;
  int gemm_grid = (N + TM - 1) / TM;
  for (int l = 0; l < 5; ++l) {
    bscale /= S;
    gemm_fused<<<gemm_grid, 256, 0, stream>>>(hin, row_ptr, col,
                                              Whi + (size_t)l * 32768, Wlo + (size_t)l * 32768,
                                              (const float*)d_in[5 + 3 * l], bscale, hout, N);
    hin = hout;
    hout = (hout == bufA) ? bufB : bufA;
  }
  poolhead_kernel<<<G, 128, 0, stream>>>(hin, batch,
                                         (const float*)d_in[19], (const float*)d_in[20],
                                         (const float*)d_in[21], (const float*)d_in[22],
                                         (float*)d_out, N, 32768.0f);
}

// Round 7
// 376.940 us; speedup vs baseline: 1.9857x; 1.0171x over previous
//
#include <hip/hip_runtime.h>
#include <hip/hip_bf16.h>

typedef __attribute__((ext_vector_type(4))) float f32x4;
typedef __attribute__((ext_vector_type(8))) _Float16 f16x8;
typedef __attribute__((ext_vector_type(4))) _Float16 f16x4;

#define CHUNK 4096   // edges per pass-1 block
#define BSH 7        // nodes per bucket = 128
#define CAP 4096     // max edges per bucket handled in LDS fast path
#define TM 32        // rows per gemm block

// ---------------- fp32 -> fp16 convert ----------------
__global__ __launch_bounds__(256) void cvt_kernel(const float* __restrict__ x,
                                                  _Float16* __restrict__ h, int total4) {
  int i = blockIdx.x * blockDim.x + threadIdx.x;
  if (i < total4) {
    float4 v = *(const float4*)(x + (size_t)i * 4);
    f16x4 o = {(_Float16)v.x, (_Float16)v.y, (_Float16)v.z, (_Float16)v.w};
    *(f16x4*)(h + (size_t)i * 4) = o;
  }
}

// ---------------- CSR build: bucketed counting sort ----------------
__global__ __launch_bounds__(256) void bhist_kernel(const int* __restrict__ dst,
                                                    int* __restrict__ gcnt, int E, int nb) {
  __shared__ int l[512];
  int t = threadIdx.x;
  for (int i = t; i < 512; i += 256) l[i] = 0;
  __syncthreads();
  int cbase = blockIdx.x * CHUNK;
  #pragma unroll
  for (int i = 0; i < CHUNK / 256; ++i) {
    int idx = cbase + i * 256 + t;
    if (idx < E) atomicAdd(&l[dst[idx] >> BSH], 1);
  }
  __syncthreads();
  for (int i = t; i < nb; i += 256) {
    int c = l[i];
    if (c) atomicAdd(&gcnt[i], c);
  }
}

__global__ __launch_bounds__(512) void bscan_kernel(const int* __restrict__ gcnt,
                                                    int* __restrict__ base,
                                                    int* __restrict__ gcursor, int nb, int E) {
  __shared__ int wsum[8], wpre[8];
  int t = threadIdx.x, lane = t & 63, w = t >> 6;
  int v = (t < nb) ? gcnt[t] : 0;
  int incl = v;
  #pragma unroll
  for (int o = 1; o < 64; o <<= 1) {
    int x = __shfl_up(incl, o, 64);
    if (lane >= o) incl += x;
  }
  if (lane == 63) wsum[w] = incl;
  __syncthreads();
  if (t == 0) {
    int run = 0;
    #pragma unroll
    for (int q = 0; q < 8; ++q) { wpre[q] = run; run += wsum[q]; }
  }
  __syncthreads();
  int excl = wpre[w] + incl - v;
  if (t < nb) { base[t] = excl; gcursor[t] = excl; }
  if (t == 0) base[nb] = E;
}

__global__ __launch_bounds__(256) void bscatter_kernel(const int* __restrict__ src,
                                                       const int* __restrict__ dst,
                                                       int* __restrict__ gcursor,
                                                       int2* __restrict__ pairs, int E, int nb) {
  __shared__ int lcnt[512], lstart[512], lpos[512], lgbase[512];
  __shared__ int2 lp[CHUNK];
  __shared__ int wsum[4], wpre[4];
  int t = threadIdx.x, lane = t & 63, w = t >> 6;
  for (int i = t; i < 512; i += 256) lcnt[i] = 0;
  __syncthreads();
  int cbase = blockIdx.x * CHUNK;
  int m = E - cbase; if (m > CHUNK) m = CHUNK;
  #pragma unroll
  for (int i = 0; i < CHUNK / 256; ++i) {
    int idx = i * 256 + t;
    if (idx < m) atomicAdd(&lcnt[dst[cbase + idx] >> BSH], 1);
  }
  __syncthreads();
  int c0 = lcnt[2 * t], c1 = lcnt[2 * t + 1];
  int s = c0 + c1, incl = s;
  #pragma unroll
  for (int o = 1; o < 64; o <<= 1) {
    int x = __shfl_up(incl, o, 64);
    if (lane >= o) incl += x;
  }
  if (lane == 63) wsum[w] = incl;
  __syncthreads();
  if (t == 0) {
    int run = 0;
    #pragma unroll
    for (int q = 0; q < 4; ++q) { wpre[q] = run; run += wsum[q]; }
  }
  __syncthreads();
  int excl = wpre[w] + incl - s;
  lstart[2 * t] = excl;          lpos[2 * t] = excl;
  lstart[2 * t + 1] = excl + c0; lpos[2 * t + 1] = excl + c0;
  if (2 * t < nb && c0 > 0) lgbase[2 * t] = atomicAdd(&gcursor[2 * t], c0);
  if (2 * t + 1 < nb && c1 > 0) lgbase[2 * t + 1] = atomicAdd(&gcursor[2 * t + 1], c1);
  __syncthreads();
  #pragma unroll
  for (int i = 0; i < CHUNK / 256; ++i) {
    int idx = i * 256 + t;
    if (idx < m) {
      int d = dst[cbase + idx], sv = src[cbase + idx];
      int p = atomicAdd(&lpos[d >> BSH], 1);
      lp[p] = make_int2(sv, d);
    }
  }
  __syncthreads();
  for (int i = t; i < m; i += 256) {
    int2 pr = lp[i];
    int b = pr.y >> BSH;
    pairs[lgbase[b] + (i - lstart[b])] = pr;
  }
}

__global__ __launch_bounds__(256) void bbuild_kernel(const int2* __restrict__ pairs,
                                                     const int* __restrict__ base,
                                                     int* __restrict__ row_ptr,
                                                     int* __restrict__ col, int N, int E) {
  __shared__ int cnt[128], cur[128], w2[2];
  __shared__ int cl[CAP];
  int b = blockIdx.x, t = threadIdx.x;
  int mb = base[b], me = base[b + 1], m = me - mb;
  if (t < 128) cnt[t] = 0;
  __syncthreads();
  for (int i = t; i < m; i += 256) atomicAdd(&cnt[pairs[mb + i].y & 127], 1);
  __syncthreads();
  int v = 0, incl = 0;
  if (t < 128) {
    v = cnt[t]; incl = v;
    #pragma unroll
    for (int o = 1; o < 64; o <<= 1) {
      int x = __shfl_up(incl, o, 64);
      if ((t & 63) >= o) incl += x;
    }
    if ((t & 63) == 63) w2[t >> 6] = incl;
  }
  __syncthreads();
  if (t < 128) {
    int excl = incl - v + ((t & 64) ? w2[0] : 0);
    cur[t] = excl;
    int node = (b << BSH) + t;
    if (node < N) row_ptr[node] = mb + excl;
  }
  if (b == 0 && t == 0) row_ptr[N] = E;
  __syncthreads();
  if (m <= CAP) {
    for (int i = t; i < m; i += 256) {
      int2 p = pairs[mb + i];
      int pos = atomicAdd(&cur[p.y & 127], 1);
      cl[pos] = p.x;
    }
    __syncthreads();
    for (int i = t; i < m; i += 256) col[mb + i] = cl[i];
  } else {
    for (int i = t; i < m; i += 256) {
      int2 p = pairs[mb + i];
      int pos = atomicAdd(&cur[p.y & 127], 1);
      col[mb + pos] = p.x;
    }
  }
}

// ---------------- weight prep: all 5 layers in one launch ----------------
struct W10 { const float* p[10]; };  // p[0..4]=Wrel, p[5..9]=Wroot

__global__ __launch_bounds__(256) void prep_kernel(W10 wp, _Float16* __restrict__ Whi,
                                                   _Float16* __restrict__ Wlo, float wscale) {
  int l = blockIdx.x >> 7;
  int idx = (blockIdx.x & 127) * 256 + threadIdx.x;  // col*256 + k
  int col = idx >> 8;
  int k = idx & 255;
  const float* __restrict__ Wrel = wp.p[l];
  const float* __restrict__ Wroot = wp.p[5 + l];
  float v = (k < 128) ? Wrel[k * 128 + col] : Wroot[(k - 128) * 128 + col];
  v *= wscale;
  _Float16 hi = (_Float16)v;
  _Float16 lo = (_Float16)(v - (float)hi);
  Whi[(size_t)l * 32768 + idx] = hi;
  Wlo[(size_t)l * 32768 + idx] = lo;
}

// ---------------- fused gather + GEMM, 32-row tile, dual-row pipelined gather ----------------
// out = relu(concat[sum_{nbr} h, h] @ Wcat + b*bscale), fp16 in/out
__global__ __launch_bounds__(256) void gemm_fused(const _Float16* __restrict__ hin,
                                                  const int* __restrict__ row_ptr,
                                                  const int* __restrict__ col,
                                                  const _Float16* __restrict__ Whi,
                                                  const _Float16* __restrict__ Wlo,
                                                  const float* __restrict__ bias,
                                                  float bscale,
                                                  _Float16* __restrict__ out, int N) {
  __shared__ unsigned lds[TM * 64];  // agg tile [32 rows][64 u32], XOR-swizzled
  const char* __restrict__ hb = (const char*)hin;
  int t = threadIdx.x, w = t >> 6, lane = t & 63;
  int g = lane >> 4, l16 = lane & 15;
  unsigned lofs = (unsigned)l16 << 4;
  int row_base = blockIdx.x * TM;

  // ---- gather: each 16-lane group runs TWO rows (A,B) concurrently ----
  int rA = w * 8 + g, rB = rA + 4;          // local rows 0..31
  int rowA = row_base + rA, rowB = row_base + rB;
  float accA[8], accB[8];
  #pragma unroll
  for (int q = 0; q < 8; ++q) { accA[q] = 0.f; accB[q] = 0.f; }
  int sA = 0, eA = 0, sB = 0, eB = 0;
  if (rowA < N) { sA = row_ptr[rowA]; eA = row_ptr[rowA + 1]; }
  if (rowB < N) { sB = row_ptr[rowB]; eB = row_ptr[rowB + 1]; }
  int cA[8], cB[8];
  #pragma unroll
  for (int q = 0; q < 8; ++q) {
    int ia = sA + q; cA[q] = (sA < eA) ? col[ia < eA ? ia : eA - 1] : 0;
    int ib = sB + q; cB[q] = (sB < eB) ? col[ib < eB ? ib : eB - 1] : 0;
  }
  int iA = sA, iB = sB;
  // unified loop: 16 gathers (16 KB/wave) in flight
  while (iA + 8 <= eA && iB + 8 <= eB) {
    f16x8 vA[8], vB[8];
    #pragma unroll
    for (int q = 0; q < 8; ++q) vA[q] = *(const f16x8*)(hb + ((((unsigned)cA[q]) << 8) | lofs));
    #pragma unroll
    for (int q = 0; q < 8; ++q) vB[q] = *(const f16x8*)(hb + ((((unsigned)cB[q]) << 8) | lofs));
    #pragma unroll
    for (int q = 0; q < 8; ++q) { int x = iA + 8 + q; cA[q] = col[x < eA ? x : eA - 1]; }
    #pragma unroll
    for (int q = 0; q < 8; ++q) { int x = iB + 8 + q; cB[q] = col[x < eB ? x : eB - 1]; }
    #pragma unroll
    for (int z = 0; z < 8; ++z)
      accA[z] += (((float)vA[0][z] + (float)vA[1][z]) + ((float)vA[2][z] + (float)vA[3][z])) +
                 (((float)vA[4][z] + (float)vA[5][z]) + ((float)vA[6][z] + (float)vA[7][z]));
    #pragma unroll
    for (int z = 0; z < 8; ++z)
      accB[z] += (((float)vB[0][z] + (float)vB[1][z]) + ((float)vB[2][z] + (float)vB[3][z])) +
                 (((float)vB[4][z] + (float)vB[5][z]) + ((float)vB[6][z] + (float)vB[7][z]));
    iA += 8; iB += 8;
  }
  // drain A
  while (iA + 8 <= eA) {
    f16x8 v[8];
    #pragma unroll
    for (int q = 0; q < 8; ++q) v[q] = *(const f16x8*)(hb + ((((unsigned)cA[q]) << 8) | lofs));
    #pragma unroll
    for (int q = 0; q < 8; ++q) { int x = iA + 8 + q; cA[q] = col[x < eA ? x : eA - 1]; }
    #pragma unroll
    for (int z = 0; z < 8; ++z)
      accA[z] += (((float)v[0][z] + (float)v[1][z]) + ((float)v[2][z] + (float)v[3][z])) +
                 (((float)v[4][z] + (float)v[5][z]) + ((float)v[6][z] + (float)v[7][z]));
    iA += 8;
  }
  // drain B
  while (iB + 8 <= eB) {
    f16x8 v[8];
    #pragma unroll
    for (int q = 0; q < 8; ++q) v[q] = *(const f16x8*)(hb + ((((unsigned)cB[q]) << 8) | lofs));
    #pragma unroll
    for (int q = 0; q < 8; ++q) { int x = iB + 8 + q; cB[q] = col[x < eB ? x : eB - 1]; }
    #pragma unroll
    for (int z = 0; z < 8; ++z)
      accB[z] += (((float)v[0][z] + (float)v[1][z]) + ((float)v[2][z] + (float)v[3][z])) +
                 (((float)v[4][z] + (float)v[5][z]) + ((float)v[6][z] + (float)v[7][z]));
    iB += 8;
  }
  // masked tails (c arrays already hold clamped indices for [i, i+8))
  if (iA < eA) {
    f16x8 v[8];
    #pragma unroll
    for (int q = 0; q < 8; ++q) v[q] = *(const f16x8*)(hb + ((((unsigned)cA[q]) << 8) | lofs));
    #pragma unroll
    for (int q = 0; q < 8; ++q) {
      float m = (iA + q < eA) ? 1.f : 0.f;
      #pragma unroll
      for (int z = 0; z < 8; ++z) accA[z] = fmaf(m, (float)v[q][z], accA[z]);
    }
  }
  if (iB < eB) {
    f16x8 v[8];
    #pragma unroll
    for (int q = 0; q < 8; ++q) v[q] = *(const f16x8*)(hb + ((((unsigned)cB[q]) << 8) | lofs));
    #pragma unroll
    for (int q = 0; q < 8; ++q) {
      float m = (iB + q < eB) ? 1.f : 0.f;
      #pragma unroll
      for (int z = 0; z < 8; ++z) accB[z] = fmaf(m, (float)v[q][z], accB[z]);
    }
  }
  {
    f16x8 oA, oB;
    #pragma unroll
    for (int q = 0; q < 8; ++q) { oA[q] = (_Float16)accA[q]; oB[q] = (_Float16)accB[q]; }
    unsigned byteA = (unsigned)(rA * 256 + l16 * 16) ^ (unsigned)((rA & 7) << 4);
    unsigned byteB = (unsigned)(rB * 256 + l16 * 16) ^ (unsigned)((rB & 7) << 4);
    *(f16x8*)((char*)lds + byteA) = oA;
    *(f16x8*)((char*)lds + byteB) = oB;
  }
  __syncthreads();

  // ---- MFMA phase: 32 rows x 128 cols; wave w owns cols w*32..+32 ----
  int khalf = lane >> 4;  // 0..3
  int koff = khalf * 8;
  int col_base = w * 32;

  f32x4 acc[2][2];
  #pragma unroll
  for (int r = 0; r < 2; r++)
    #pragma unroll
    for (int c = 0; c < 2; c++) acc[r][c] = (f32x4){0.f, 0.f, 0.f, 0.f};

  __builtin_amdgcn_s_setprio(1);
  #pragma unroll
  for (int ks = 0; ks < 8; ++ks) {
    int k0 = ks * 32;
    f16x8 bh[2], bl[2];
    #pragma unroll
    for (int c = 0; c < 2; c++) {
      int cc = col_base + c * 16 + l16;
      bh[c] = *(const f16x8*)(Whi + cc * 256 + k0 + koff);
      bl[c] = *(const f16x8*)(Wlo + cc * 256 + k0 + koff);
    }
    #pragma unroll
    for (int r = 0; r < 2; r++) {
      f16x8 a;
      if (ks < 4) {
        int arow = r * 16 + l16;
        unsigned byte = (unsigned)(arow * 256 + k0 * 2 + khalf * 16) ^ (unsigned)((arow & 7) << 4);
        a = *(const f16x8*)((const char*)lds + byte);
      } else {
        int row = row_base + r * 16 + l16;
        if (row >= N) row = N - 1;
        a = *(const f16x8*)(hin + (size_t)row * 128 + (k0 - 128) + koff);
      }
      #pragma unroll
      for (int c = 0; c < 2; c++) {
        acc[r][c] = __builtin_amdgcn_mfma_f32_16x16x32_f16(a, bh[c], acc[r][c], 0, 0, 0);
        acc[r][c] = __builtin_amdgcn_mfma_f32_16x16x32_f16(a, bl[c], acc[r][c], 0, 0, 0);
      }
    }
  }
  __builtin_amdgcn_s_setprio(0);

  #pragma unroll
  for (int r = 0; r < 2; r++) {
    #pragma unroll
    for (int c = 0; c < 2; c++) {
      int cc = col_base + c * 16 + l16;
      float b = bias[cc] * bscale;
      #pragma unroll
      for (int tt = 0; tt < 4; tt++) {
        int row = row_base + r * 16 + khalf * 4 + tt;
        if (row < N) {
          float v = acc[r][c][tt] + b;
          out[(size_t)row * 128 + cc] = (_Float16)(v > 0.f ? v : 0.f);
        }
      }
    }
  }
}

// ---------------- fused pool + MLP head (batch sorted) ----------------
static __device__ __forceinline__ int lbound(const int* __restrict__ a, int n, int v) {
  int lo = 0, hi = n;
  while (lo < hi) {
    int m = (lo + hi) >> 1;
    if (a[m] < v) lo = m + 1; else hi = m;
  }
  return lo;
}

__global__ __launch_bounds__(128) void poolhead_kernel(const _Float16* __restrict__ h,
                                                       const int* __restrict__ batch,
                                                       const float* __restrict__ fc1W,
                                                       const float* __restrict__ fc1b,
                                                       const float* __restrict__ fc2W,
                                                       const float* __restrict__ fc2b,
                                                       float* __restrict__ out, int N,
                                                       float unscale) {
  int gid = blockIdx.x, j = threadIdx.x;
  int start = lbound(batch, N, gid);
  int end = lbound(batch, N, gid + 1);
  float acc = 0.f;
  int r = start;
  for (; r + 3 < end; r += 4) {
    acc += (float)h[(size_t)r * 128 + j] + (float)h[(size_t)(r + 1) * 128 + j] +
           (float)h[(size_t)(r + 2) * 128 + j] + (float)h[(size_t)(r + 3) * 128 + j];
  }
  for (; r < end; ++r) acc += (float)h[(size_t)r * 128 + j];
  __shared__ float grow[128];
  __shared__ float red[128];
  grow[j] = acc * unscale;
  __syncthreads();
  float a1 = fc1b[j];
  #pragma unroll 8
  for (int k = 0; k < 128; ++k) a1 = fmaf(grow[k], fc1W[k * 128 + j], a1);
  a1 = a1 > 0.f ? a1 : 0.f;
  red[j] = a1 * fc2W[j];
  __syncthreads();
  #pragma unroll
  for (int s2 = 64; s2 > 0; s2 >>= 1) {
    if (j < s2) red[j] += red[j + s2];
    __syncthreads();
  }
  if (j == 0) out[gid] = red[0] + fc2b[0];
}

extern "C" void kernel_launch(void* const* d_in, const int* in_sizes, int n_in,
                              void* d_out, int out_size, void* d_ws, size_t ws_size,
                              hipStream_t stream) {
  const float* x = (const float*)d_in[0];
  const int* edge = (const int*)d_in[1];
  const int* batch = (const int*)d_in[2];
  const int N = in_sizes[0] / 128;
  const int E = in_sizes[1] / 2;
  const int G = out_size;
  const int* esrc = edge;
  const int* edst = edge + E;
  const int NB = (N + 127) >> BSH;  // buckets

  char* ws = (char*)d_ws;
  size_t off = 0;
  auto alloc = [&](size_t bytes) -> void* {
    void* p = ws + off;
    off = (off + bytes + 255) & ~(size_t)255;
    return p;
  };
  _Float16* x16  = (_Float16*)alloc((size_t)N * 128 * 2);
  _Float16* bufA = (_Float16*)alloc((size_t)N * 128 * 2);
  _Float16* bufB = (_Float16*)alloc((size_t)N * 128 * 2);
  _Float16* Whi  = (_Float16*)alloc((size_t)5 * 32768 * 2);
  _Float16* Wlo  = (_Float16*)alloc((size_t)5 * 32768 * 2);
  int* row_ptr   = (int*)alloc((size_t)(N + 1) * 4);
  int* col       = (int*)alloc((size_t)E * 4);
  int2* pairs    = (int2*)alloc((size_t)E * 8);
  int* gcnt      = (int*)alloc(512 * 4);
  int* base      = (int*)alloc(520 * 4);
  int* gcursor   = (int*)alloc(512 * 4);
  if (off > ws_size) return;  // fail loudly

  hipMemsetAsync(gcnt, 0, 512 * 4, stream);

  int nb1 = (E + CHUNK - 1) / CHUNK;
  bhist_kernel<<<nb1, 256, 0, stream>>>(edst, gcnt, E, NB);
  bscan_kernel<<<1, 512, 0, stream>>>(gcnt, base, gcursor, NB, E);
  bscatter_kernel<<<nb1, 256, 0, stream>>>(esrc, edst, gcursor, pairs, E, NB);
  bbuild_kernel<<<NB, 256, 0, stream>>>(pairs, base, row_ptr, col, N, E);

  cvt_kernel<<<(N * 128 / 4 + 255) / 256, 256, 0, stream>>>(x, x16, N * 128 / 4);

  // h'_l = h_l / 8^l keeps fp16 in range; weights *1/8, bias *8^-(l+1), undone at pool.
  const float S = 8.0f;
  W10 wp;
  for (int l = 0; l < 5; ++l) {
    wp.p[l] = (const float*)d_in[4 + 3 * l];
    wp.p[5 + l] = (const float*)d_in[6 + 3 * l];
  }
  prep_kernel<<<640, 256, 0, stream>>>(wp, Whi, Wlo, 1.0f / S);

  const _Float16* hin = x16;
  _Float16* hout = bufA;
  int gemm_grid = (N + TM - 1) / TM;
  float bscale = 1.0f;
  for (int l = 0; l < 5; ++l) {
    bscale /= S;
    gemm_fused<<<gemm_grid, 256, 0, stream>>>(hin, row_ptr, col,
                                              Whi + (size_t)l * 32768, Wlo + (size_t)l * 32768,
                                              (const float*)d_in[5 + 3 * l], bscale, hout, N);
    hin = hout;
    hout = (hout == bufA) ? bufB : bufA;
  }
  poolhead_kernel<<<G, 128, 0, stream>>>(hin, batch,
                                         (const float*)d_in[19], (const float*)d_in[20],
                                         (const float*)d_in[21], (const float*)d_in[22],
                                         (float*)d_out, N, 32768.0f);
}

// Round 8
// 374.404 us; speedup vs baseline: 1.9992x; 1.0068x over previous
//
#include <hip/hip_runtime.h>
#include <hip/hip_bf16.h>

typedef __attribute__((ext_vector_type(4))) float f32x4;
typedef __attribute__((ext_vector_type(8))) _Float16 f16x8;
typedef __attribute__((ext_vector_type(4))) _Float16 f16x4;

#define CHUNK 4096   // edges per pass-1 block
#define BSH 7        // nodes per bucket = 128
#define CAP 4096     // max edges per bucket handled in LDS fast path

// ---------------- fp32 -> fp16 convert ----------------
__global__ __launch_bounds__(256) void cvt_kernel(const float* __restrict__ x,
                                                  _Float16* __restrict__ h, int total4) {
  int i = blockIdx.x * blockDim.x + threadIdx.x;
  if (i < total4) {
    float4 v = *(const float4*)(x + (size_t)i * 4);
    f16x4 o = {(_Float16)v.x, (_Float16)v.y, (_Float16)v.z, (_Float16)v.w};
    *(f16x4*)(h + (size_t)i * 4) = o;
  }
}

// ---------------- CSR build: bucketed counting sort ----------------
__global__ __launch_bounds__(256) void bhist_kernel(const int* __restrict__ dst,
                                                    int* __restrict__ gcnt, int E, int nb) {
  __shared__ int l[512];
  int t = threadIdx.x;
  for (int i = t; i < 512; i += 256) l[i] = 0;
  __syncthreads();
  int cbase = blockIdx.x * CHUNK;
  #pragma unroll
  for (int i = 0; i < CHUNK / 256; ++i) {
    int idx = cbase + i * 256 + t;
    if (idx < E) atomicAdd(&l[dst[idx] >> BSH], 1);
  }
  __syncthreads();
  for (int i = t; i < nb; i += 256) {
    int c = l[i];
    if (c) atomicAdd(&gcnt[i], c);
  }
}

__global__ __launch_bounds__(512) void bscan_kernel(const int* __restrict__ gcnt,
                                                    int* __restrict__ base,
                                                    int* __restrict__ gcursor, int nb, int E) {
  __shared__ int wsum[8], wpre[8];
  int t = threadIdx.x, lane = t & 63, w = t >> 6;
  int v = (t < nb) ? gcnt[t] : 0;
  int incl = v;
  #pragma unroll
  for (int o = 1; o < 64; o <<= 1) {
    int x = __shfl_up(incl, o, 64);
    if (lane >= o) incl += x;
  }
  if (lane == 63) wsum[w] = incl;
  __syncthreads();
  if (t == 0) {
    int run = 0;
    #pragma unroll
    for (int q = 0; q < 8; ++q) { wpre[q] = run; run += wsum[q]; }
  }
  __syncthreads();
  int excl = wpre[w] + incl - v;
  if (t < nb) { base[t] = excl; gcursor[t] = excl; }
  if (t == 0) base[nb] = E;
}

__global__ __launch_bounds__(256) void bscatter_kernel(const int* __restrict__ src,
                                                       const int* __restrict__ dst,
                                                       int* __restrict__ gcursor,
                                                       int2* __restrict__ pairs, int E, int nb) {
  __shared__ int lcnt[512], lstart[512], lpos[512], lgbase[512];
  __shared__ int2 lp[CHUNK];
  __shared__ int wsum[4], wpre[4];
  int t = threadIdx.x, lane = t & 63, w = t >> 6;
  for (int i = t; i < 512; i += 256) lcnt[i] = 0;
  __syncthreads();
  int cbase = blockIdx.x * CHUNK;
  int m = E - cbase; if (m > CHUNK) m = CHUNK;
  #pragma unroll
  for (int i = 0; i < CHUNK / 256; ++i) {
    int idx = i * 256 + t;
    if (idx < m) atomicAdd(&lcnt[dst[cbase + idx] >> BSH], 1);
  }
  __syncthreads();
  int c0 = lcnt[2 * t], c1 = lcnt[2 * t + 1];
  int s = c0 + c1, incl = s;
  #pragma unroll
  for (int o = 1; o < 64; o <<= 1) {
    int x = __shfl_up(incl, o, 64);
    if (lane >= o) incl += x;
  }
  if (lane == 63) wsum[w] = incl;
  __syncthreads();
  if (t == 0) {
    int run = 0;
    #pragma unroll
    for (int q = 0; q < 4; ++q) { wpre[q] = run; run += wsum[q]; }
  }
  __syncthreads();
  int excl = wpre[w] + incl - s;
  lstart[2 * t] = excl;          lpos[2 * t] = excl;
  lstart[2 * t + 1] = excl + c0; lpos[2 * t + 1] = excl + c0;
  if (2 * t < nb && c0 > 0) lgbase[2 * t] = atomicAdd(&gcursor[2 * t], c0);
  if (2 * t + 1 < nb && c1 > 0) lgbase[2 * t + 1] = atomicAdd(&gcursor[2 * t + 1], c1);
  __syncthreads();
  #pragma unroll
  for (int i = 0; i < CHUNK / 256; ++i) {
    int idx = i * 256 + t;
    if (idx < m) {
      int d = dst[cbase + idx], sv = src[cbase + idx];
      int p = atomicAdd(&lpos[d >> BSH], 1);
      lp[p] = make_int2(sv, d);
    }
  }
  __syncthreads();
  for (int i = t; i < m; i += 256) {
    int2 pr = lp[i];
    int b = pr.y >> BSH;
    pairs[lgbase[b] + (i - lstart[b])] = pr;
  }
}

__global__ __launch_bounds__(256) void bbuild_kernel(const int2* __restrict__ pairs,
                                                     const int* __restrict__ base,
                                                     int* __restrict__ row_ptr,
                                                     int* __restrict__ col, int N, int E) {
  __shared__ int cnt[128], cur[128], w2[2];
  __shared__ int cl[CAP];
  int b = blockIdx.x, t = threadIdx.x;
  int mb = base[b], me = base[b + 1], m = me - mb;
  if (t < 128) cnt[t] = 0;
  __syncthreads();
  for (int i = t; i < m; i += 256) atomicAdd(&cnt[pairs[mb + i].y & 127], 1);
  __syncthreads();
  int v = 0, incl = 0;
  if (t < 128) {
    v = cnt[t]; incl = v;
    #pragma unroll
    for (int o = 1; o < 64; o <<= 1) {
      int x = __shfl_up(incl, o, 64);
      if ((t & 63) >= o) incl += x;
    }
    if ((t & 63) == 63) w2[t >> 6] = incl;
  }
  __syncthreads();
  if (t < 128) {
    int excl = incl - v + ((t & 64) ? w2[0] : 0);
    cur[t] = excl;
    int node = (b << BSH) + t;
    if (node < N) row_ptr[node] = mb + excl;
  }
  if (b == 0 && t == 0) row_ptr[N] = E;
  __syncthreads();
  if (m <= CAP) {
    for (int i = t; i < m; i += 256) {
      int2 p = pairs[mb + i];
      int pos = atomicAdd(&cur[p.y & 127], 1);
      cl[pos] = p.x;
    }
    __syncthreads();
    for (int i = t; i < m; i += 256) col[mb + i] = cl[i];
  } else {
    for (int i = t; i < m; i += 256) {
      int2 p = pairs[mb + i];
      int pos = atomicAdd(&cur[p.y & 127], 1);
      col[mb + pos] = p.x;
    }
  }
}

// ---------------- weight prep: all 5 layers in one launch ----------------
struct W10 { const float* p[10]; };  // p[0..4]=Wrel, p[5..9]=Wroot

__global__ __launch_bounds__(256) void prep_kernel(W10 wp, _Float16* __restrict__ Whi,
                                                   _Float16* __restrict__ Wlo, float wscale) {
  int l = blockIdx.x >> 7;
  int idx = (blockIdx.x & 127) * 256 + threadIdx.x;  // col*256 + k
  int col = idx >> 8;
  int k = idx & 255;
  const float* __restrict__ Wrel = wp.p[l];
  const float* __restrict__ Wroot = wp.p[5 + l];
  float v = (k < 128) ? Wrel[k * 128 + col] : Wroot[(k - 128) * 128 + col];
  v *= wscale;
  _Float16 hi = (_Float16)v;
  _Float16 lo = (_Float16)(v - (float)hi);
  Whi[(size_t)l * 32768 + idx] = hi;
  Wlo[(size_t)l * 32768 + idx] = lo;
}

// ---------------- standalone SpMM: one row per 16-lane group, 8-deep pipeline ----------------
__global__ __launch_bounds__(256) void spmm_kernel(const _Float16* __restrict__ hin,
                                                   const int* __restrict__ row_ptr,
                                                   const int* __restrict__ col,
                                                   _Float16* __restrict__ agg, int N) {
  int t = threadIdx.x;
  int grp = t >> 4, l16 = t & 15;
  int row = blockIdx.x * 16 + grp;
  if (row >= N) return;
  const char* __restrict__ hb = (const char*)hin;
  unsigned lofs = (unsigned)l16 << 4;
  int s = row_ptr[row], e = row_ptr[row + 1];
  float acc[8];
  #pragma unroll
  for (int q = 0; q < 8; ++q) acc[q] = 0.f;
  if (s < e) {
    int c[8];
    #pragma unroll
    for (int q = 0; q < 8; ++q) { int x = s + q; c[q] = col[x < e ? x : e - 1]; }
    int i = s;
    for (; i + 8 <= e; i += 8) {
      f16x8 v[8];
      #pragma unroll
      for (int q = 0; q < 8; ++q) v[q] = *(const f16x8*)(hb + ((((unsigned)c[q]) << 8) | lofs));
      #pragma unroll
      for (int q = 0; q < 8; ++q) { int x = i + 8 + q; c[q] = col[x < e ? x : e - 1]; }
      #pragma unroll
      for (int z = 0; z < 8; ++z)
        acc[z] += (((float)v[0][z] + (float)v[1][z]) + ((float)v[2][z] + (float)v[3][z])) +
                  (((float)v[4][z] + (float)v[5][z]) + ((float)v[6][z] + (float)v[7][z]));
    }
    if (i < e) {  // masked tail, c[] holds clamped indices
      f16x8 v[8];
      #pragma unroll
      for (int q = 0; q < 8; ++q) v[q] = *(const f16x8*)(hb + ((((unsigned)c[q]) << 8) | lofs));
      #pragma unroll
      for (int q = 0; q < 8; ++q) {
        float m = (i + q < e) ? 1.f : 0.f;
        #pragma unroll
        for (int z = 0; z < 8; ++z) acc[z] = fmaf(m, (float)v[q][z], acc[z]);
      }
    }
  }
  f16x8 o;
  #pragma unroll
  for (int q = 0; q < 8; ++q) o[q] = (_Float16)acc[q];
  *(f16x8*)(agg + (size_t)row * 128 + l16 * 8) = o;
}

// ---------------- dense GEMM: out = relu(concat[agg,h] @ Wcat + b*bscale) ----------------
__global__ __launch_bounds__(256) void gemm_kernel(const _Float16* __restrict__ Aagg,
                                                   const _Float16* __restrict__ Ah,
                                                   const _Float16* __restrict__ Whi,
                                                   const _Float16* __restrict__ Wlo,
                                                   const float* __restrict__ bias,
                                                   float bscale,
                                                   _Float16* __restrict__ out, int N) {
  int wv = threadIdx.x >> 6;
  int lane = threadIdx.x & 63;
  int l16 = lane & 15;
  int khalf = lane >> 4;  // 0..3
  int koff = khalf * 8;
  int row_base = blockIdx.x * 64;
  int col_base = wv * 32;

  f32x4 acc[4][2];
  #pragma unroll
  for (int r = 0; r < 4; r++)
    #pragma unroll
    for (int c = 0; c < 2; c++) acc[r][c] = (f32x4){0.f, 0.f, 0.f, 0.f};

  #pragma unroll
  for (int ks = 0; ks < 8; ++ks) {
    int k0 = ks * 32;
    const _Float16* Abase = (ks < 4) ? (Aagg + k0) : (Ah + (k0 - 128));
    f16x8 bh[2], bl[2];
    #pragma unroll
    for (int c = 0; c < 2; c++) {
      int col = col_base + c * 16 + l16;
      bh[c] = *(const f16x8*)(Whi + col * 256 + k0 + koff);
      bl[c] = *(const f16x8*)(Wlo + col * 256 + k0 + koff);
    }
    #pragma unroll
    for (int r = 0; r < 4; r++) {
      int row = row_base + r * 16 + l16;
      if (row >= N) row = N - 1;
      f16x8 a = *(const f16x8*)(Abase + (size_t)row * 128 + koff);
      #pragma unroll
      for (int c = 0; c < 2; c++) {
        acc[r][c] = __builtin_amdgcn_mfma_f32_16x16x32_f16(a, bh[c], acc[r][c], 0, 0, 0);
        acc[r][c] = __builtin_amdgcn_mfma_f32_16x16x32_f16(a, bl[c], acc[r][c], 0, 0, 0);
      }
    }
  }

  #pragma unroll
  for (int r = 0; r < 4; r++) {
    #pragma unroll
    for (int c = 0; c < 2; c++) {
      int col = col_base + c * 16 + l16;
      float b = bias[col] * bscale;
      #pragma unroll
      for (int tt = 0; tt < 4; tt++) {
        int row = row_base + r * 16 + khalf * 4 + tt;
        if (row < N) {
          float v = acc[r][c][tt] + b;
          out[(size_t)row * 128 + col] = (_Float16)(v > 0.f ? v : 0.f);
        }
      }
    }
  }
}

// ---------------- fused pool + MLP head (batch sorted) ----------------
static __device__ __forceinline__ int lbound(const int* __restrict__ a, int n, int v) {
  int lo = 0, hi = n;
  while (lo < hi) {
    int m = (lo + hi) >> 1;
    if (a[m] < v) lo = m + 1; else hi = m;
  }
  return lo;
}

__global__ __launch_bounds__(128) void poolhead_kernel(const _Float16* __restrict__ h,
                                                       const int* __restrict__ batch,
                                                       const float* __restrict__ fc1W,
                                                       const float* __restrict__ fc1b,
                                                       const float* __restrict__ fc2W,
                                                       const float* __restrict__ fc2b,
                                                       float* __restrict__ out, int N,
                                                       float unscale) {
  int gid = blockIdx.x, j = threadIdx.x;
  int start = lbound(batch, N, gid);
  int end = lbound(batch, N, gid + 1);
  float acc = 0.f;
  int r = start;
  for (; r + 3 < end; r += 4) {
    acc += (float)h[(size_t)r * 128 + j] + (float)h[(size_t)(r + 1) * 128 + j] +
           (float)h[(size_t)(r + 2) * 128 + j] + (float)h[(size_t)(r + 3) * 128 + j];
  }
  for (; r < end; ++r) acc += (float)h[(size_t)r * 128 + j];
  __shared__ float grow[128];
  __shared__ float red[128];
  grow[j] = acc * unscale;
  __syncthreads();
  float a1 = fc1b[j];
  #pragma unroll 8
  for (int k = 0; k < 128; ++k) a1 = fmaf(grow[k], fc1W[k * 128 + j], a1);
  a1 = a1 > 0.f ? a1 : 0.f;
  red[j] = a1 * fc2W[j];
  __syncthreads();
  #pragma unroll
  for (int s2 = 64; s2 > 0; s2 >>= 1) {
    if (j < s2) red[j] += red[j + s2];
    __syncthreads();
  }
  if (j == 0) out[gid] = red[0] + fc2b[0];
}

extern "C" void kernel_launch(void* const* d_in, const int* in_sizes, int n_in,
                              void* d_out, int out_size, void* d_ws, size_t ws_size,
                              hipStream_t stream) {
  const float* x = (const float*)d_in[0];
  const int* edge = (const int*)d_in[1];
  const int* batch = (const int*)d_in[2];
  const int N = in_sizes[0] / 128;
  const int E = in_sizes[1] / 2;
  const int G = out_size;
  const int* esrc = edge;
  const int* edst = edge + E;
  const int NB = (N + 127) >> BSH;  // buckets

  char* ws = (char*)d_ws;
  size_t off = 0;
  auto alloc = [&](size_t bytes) -> void* {
    void* p = ws + off;
    off = (off + bytes + 255) & ~(size_t)255;
    return p;
  };
  _Float16* x16  = (_Float16*)alloc((size_t)N * 128 * 2);
  _Float16* bufA = (_Float16*)alloc((size_t)N * 128 * 2);
  _Float16* bufB = (_Float16*)alloc((size_t)N * 128 * 2);
  _Float16* agg  = (_Float16*)alloc((size_t)N * 128 * 2);
  _Float16* Whi  = (_Float16*)alloc((size_t)5 * 32768 * 2);
  _Float16* Wlo  = (_Float16*)alloc((size_t)5 * 32768 * 2);
  int* row_ptr   = (int*)alloc((size_t)(N + 1) * 4);
  int* col       = (int*)alloc((size_t)E * 4);
  int2* pairs    = (int2*)alloc((size_t)E * 8);
  int* gcnt      = (int*)alloc(512 * 4);
  int* base      = (int*)alloc(520 * 4);
  int* gcursor   = (int*)alloc(512 * 4);
  if (off > ws_size) return;  // fail loudly

  hipMemsetAsync(gcnt, 0, 512 * 4, stream);

  int nb1 = (E + CHUNK - 1) / CHUNK;
  bhist_kernel<<<nb1, 256, 0, stream>>>(edst, gcnt, E, NB);
  bscan_kernel<<<1, 512, 0, stream>>>(gcnt, base, gcursor, NB, E);
  bscatter_kernel<<<nb1, 256, 0, stream>>>(esrc, edst, gcursor, pairs, E, NB);
  bbuild_kernel<<<NB, 256, 0, stream>>>(pairs, base, row_ptr, col, N, E);

  cvt_kernel<<<(N * 128 / 4 + 255) / 256, 256, 0, stream>>>(x, x16, N * 128 / 4);

  // h'_l = h_l / 8^l keeps fp16 in range; weights *1/8, bias *8^-(l+1), undone at pool.
  const float S = 8.0f;
  W10 wp;
  for (int l = 0; l < 5; ++l) {
    wp.p[l] = (const float*)d_in[4 + 3 * l];
    wp.p[5 + l] = (const float*)d_in[6 + 3 * l];
  }
  prep_kernel<<<640, 256, 0, stream>>>(wp, Whi, Wlo, 1.0f / S);

  const _Float16* hin = x16;
  _Float16* hout = bufA;
  int spmm_grid = (N + 15) / 16;
  int gemm_grid = (N + 63) / 64;
  float bscale = 1.0f;
  for (int l = 0; l < 5; ++l) {
    bscale /= S;
    spmm_kernel<<<spmm_grid, 256, 0, stream>>>(hin, row_ptr, col, agg, N);
    gemm_kernel<<<gemm_grid, 256, 0, stream>>>(agg, hin,
                                               Whi + (size_t)l * 32768, Wlo + (size_t)l * 32768,
                                               (const float*)d_in[5 + 3 * l], bscale, hout, N);
    hin = hout;
    hout = (hout == bufA) ? bufB : bufA;
  }
  poolhead_kernel<<<G, 128, 0, stream>>>(hin, batch,
                                         (const float*)d_in[19], (const float*)d_in[20],
                                         (const float*)d_in[21], (const float*)d_in[22],
                                         (float*)d_out, N, 32768.0f);
}

// Round 9
// 372.277 us; speedup vs baseline: 2.0106x; 1.0057x over previous
//
#include <hip/hip_runtime.h>
#include <hip/hip_bf16.h>

typedef __attribute__((ext_vector_type(4))) float f32x4;
typedef __attribute__((ext_vector_type(8))) _Float16 f16x8;
typedef __attribute__((ext_vector_type(4))) _Float16 f16x4;

#define CHUNK 4096   // edges per pass-1 block
#define BSH 7        // nodes per bucket = 128
#define CAP 4096     // max edges per bucket handled in LDS fast path

// h layout: 4 feature-quarter planes, plane p holds columns [32p,32p+32) of all
// rows contiguously: hp[p*N*32 + r*32 + c]. A plane (3.2 MB) fits each XCD L2.

// ---------------- fp32 -> fp16 convert into planes ----------------
__global__ __launch_bounds__(256) void cvt_kernel(const float* __restrict__ x,
                                                  _Float16* __restrict__ hp, int N) {
  int i = blockIdx.x * blockDim.x + threadIdx.x;  // over N*32 quads of 4 elems
  if (i < N * 32) {
    int r = i >> 5, jg = i & 31;
    float4 v = *(const float4*)(x + (size_t)r * 128 + jg * 4);
    f16x4 o = {(_Float16)v.x, (_Float16)v.y, (_Float16)v.z, (_Float16)v.w};
    int plane = jg >> 3, wc = (jg & 7) * 4;
    *(f16x4*)(hp + (size_t)plane * N * 32 + (size_t)r * 32 + wc) = o;
  }
}

// ---------------- CSR build: bucketed counting sort ----------------
__global__ __launch_bounds__(256) void bhist_kernel(const int* __restrict__ dst,
                                                    int* __restrict__ blkhist, int E, int nb) {
  __shared__ int l[512];
  int t = threadIdx.x;
  for (int i = t; i < 512; i += 256) l[i] = 0;
  __syncthreads();
  int cbase = blockIdx.x * CHUNK;
  #pragma unroll
  for (int i = 0; i < CHUNK / 256; ++i) {
    int idx = cbase + i * 256 + t;
    if (idx < E) atomicAdd(&l[dst[idx] >> BSH], 1);
  }
  __syncthreads();
  for (int i = t; i < 512; i += 256) blkhist[blockIdx.x * 512 + i] = l[i];
}

__global__ __launch_bounds__(512) void bscan_kernel(const int* __restrict__ blkhist, int nblk,
                                                    int* __restrict__ base,
                                                    int* __restrict__ gcursor, int nb, int E) {
  __shared__ int wsum[8], wpre[8];
  int t = threadIdx.x, lane = t & 63, w = t >> 6;
  int v = 0;
  int b = 0;
  for (; b + 4 <= nblk; b += 4)
    v += blkhist[b * 512 + t] + blkhist[(b + 1) * 512 + t] +
         blkhist[(b + 2) * 512 + t] + blkhist[(b + 3) * 512 + t];
  for (; b < nblk; ++b) v += blkhist[b * 512 + t];
  int incl = v;
  #pragma unroll
  for (int o = 1; o < 64; o <<= 1) {
    int x = __shfl_up(incl, o, 64);
    if (lane >= o) incl += x;
  }
  if (lane == 63) wsum[w] = incl;
  __syncthreads();
  if (t == 0) {
    int run = 0;
    #pragma unroll
    for (int q = 0; q < 8; ++q) { wpre[q] = run; run += wsum[q]; }
  }
  __syncthreads();
  int excl = wpre[w] + incl - v;
  if (t < nb) { base[t] = excl; gcursor[t] = excl; }
  if (t == 0) base[nb] = E;
}

__global__ __launch_bounds__(256) void bscatter_kernel(const int* __restrict__ src,
                                                       const int* __restrict__ dst,
                                                       int* __restrict__ gcursor,
                                                       int2* __restrict__ pairs, int E, int nb) {
  __shared__ int lcnt[512], lstart[512], lpos[512], lgbase[512];
  __shared__ int2 lp[CHUNK];
  __shared__ int wsum[4], wpre[4];
  int t = threadIdx.x, lane = t & 63, w = t >> 6;
  for (int i = t; i < 512; i += 256) lcnt[i] = 0;
  __syncthreads();
  int cbase = blockIdx.x * CHUNK;
  int m = E - cbase; if (m > CHUNK) m = CHUNK;
  #pragma unroll
  for (int i = 0; i < CHUNK / 256; ++i) {
    int idx = i * 256 + t;
    if (idx < m) atomicAdd(&lcnt[dst[cbase + idx] >> BSH], 1);
  }
  __syncthreads();
  int c0 = lcnt[2 * t], c1 = lcnt[2 * t + 1];
  int s = c0 + c1, incl = s;
  #pragma unroll
  for (int o = 1; o < 64; o <<= 1) {
    int x = __shfl_up(incl, o, 64);
    if (lane >= o) incl += x;
  }
  if (lane == 63) wsum[w] = incl;
  __syncthreads();
  if (t == 0) {
    int run = 0;
    #pragma unroll
    for (int q = 0; q < 4; ++q) { wpre[q] = run; run += wsum[q]; }
  }
  __syncthreads();
  int excl = wpre[w] + incl - s;
  lstart[2 * t] = excl;          lpos[2 * t] = excl;
  lstart[2 * t + 1] = excl + c0; lpos[2 * t + 1] = excl + c0;
  if (2 * t < nb && c0 > 0) lgbase[2 * t] = atomicAdd(&gcursor[2 * t], c0);
  if (2 * t + 1 < nb && c1 > 0) lgbase[2 * t + 1] = atomicAdd(&gcursor[2 * t + 1], c1);
  __syncthreads();
  #pragma unroll
  for (int i = 0; i < CHUNK / 256; ++i) {
    int idx = i * 256 + t;
    if (idx < m) {
      int d = dst[cbase + idx], sv = src[cbase + idx];
      int p = atomicAdd(&lpos[d >> BSH], 1);
      lp[p] = make_int2(sv, d);
    }
  }
  __syncthreads();
  for (int i = t; i < m; i += 256) {
    int2 pr = lp[i];
    int b = pr.y >> BSH;
    pairs[lgbase[b] + (i - lstart[b])] = pr;
  }
}

__global__ __launch_bounds__(256) void bbuild_kernel(const int2* __restrict__ pairs,
                                                     const int* __restrict__ base,
                                                     int* __restrict__ row_ptr,
                                                     int* __restrict__ col, int N, int E) {
  __shared__ int cnt[128], cur[128], w2[2];
  __shared__ int cl[CAP];
  int b = blockIdx.x, t = threadIdx.x;
  int mb = base[b], me = base[b + 1], m = me - mb;
  if (t < 128) cnt[t] = 0;
  __syncthreads();
  for (int i = t; i < m; i += 256) atomicAdd(&cnt[pairs[mb + i].y & 127], 1);
  __syncthreads();
  int v = 0, incl = 0;
  if (t < 128) {
    v = cnt[t]; incl = v;
    #pragma unroll
    for (int o = 1; o < 64; o <<= 1) {
      int x = __shfl_up(incl, o, 64);
      if ((t & 63) >= o) incl += x;
    }
    if ((t & 63) == 63) w2[t >> 6] = incl;
  }
  __syncthreads();
  if (t < 128) {
    int excl = incl - v + ((t & 64) ? w2[0] : 0);
    cur[t] = excl;
    int node = (b << BSH) + t;
    if (node < N) row_ptr[node] = mb + excl;
  }
  if (b == 0 && t == 0) row_ptr[N] = E;
  __syncthreads();
  if (m <= CAP) {
    for (int i = t; i < m; i += 256) {
      int2 p = pairs[mb + i];
      int pos = atomicAdd(&cur[p.y & 127], 1);
      cl[pos] = p.x;
    }
    __syncthreads();
    for (int i = t; i < m; i += 256) col[mb + i] = cl[i];
  } else {
    for (int i = t; i < m; i += 256) {
      int2 p = pairs[mb + i];
      int pos = atomicAdd(&cur[p.y & 127], 1);
      col[mb + pos] = p.x;
    }
  }
}

// ---------------- weight prep: all 5 layers in one launch ----------------
struct W10 { const float* p[10]; };  // p[0..4]=Wrel, p[5..9]=Wroot

__global__ __launch_bounds__(256) void prep_kernel(W10 wp, _Float16* __restrict__ Whi,
                                                   _Float16* __restrict__ Wlo, float wscale) {
  int l = blockIdx.x >> 7;
  int idx = (blockIdx.x & 127) * 256 + threadIdx.x;  // col*256 + k
  int col = idx >> 8;
  int k = idx & 255;
  const float* __restrict__ Wrel = wp.p[l];
  const float* __restrict__ Wroot = wp.p[5 + l];
  float v = (k < 128) ? Wrel[k * 128 + col] : Wroot[(k - 128) * 128 + col];
  v *= wscale;
  _Float16 hi = (_Float16)v;
  _Float16 lo = (_Float16)(v - (float)hi);
  Whi[(size_t)l * 32768 + idx] = hi;
  Wlo[(size_t)l * 32768 + idx] = lo;
}

// ---------------- SpMM over feature-quarter planes ----------------
// pass p: gather 64B/edge from plane p (3.2 MB, L2-resident per XCD).
// 4-lane groups own one dst row; 8-deep col-prefetched pipeline.
__global__ __launch_bounds__(256) void spmm_kernel(const _Float16* __restrict__ hplanes,
                                                   const int* __restrict__ row_ptr,
                                                   const int* __restrict__ col,
                                                   _Float16* __restrict__ aggplanes,
                                                   int N, int nbpp) {
  int pass = blockIdx.x / nbpp;
  int blk = blockIdx.x - pass * nbpp;
  int t = threadIdx.x;
  int quad = t >> 2, lq = t & 3;
  int row = blk * 64 + quad;
  if (row >= N) return;
  size_t planeN = (size_t)N * 32;
  const char* __restrict__ hb = (const char*)(hplanes + (size_t)pass * planeN);
  unsigned lofs = (unsigned)lq << 4;
  int s = row_ptr[row], e = row_ptr[row + 1];
  float acc[8];
  #pragma unroll
  for (int q = 0; q < 8; ++q) acc[q] = 0.f;
  if (s < e) {
    int c[8];
    #pragma unroll
    for (int q = 0; q < 8; ++q) { int x = s + q; c[q] = col[x < e ? x : e - 1]; }
    int i = s;
    for (; i + 8 <= e; i += 8) {
      f16x8 v[8];
      #pragma unroll
      for (int q = 0; q < 8; ++q) v[q] = *(const f16x8*)(hb + ((((unsigned)c[q]) << 6) | lofs));
      #pragma unroll
      for (int q = 0; q < 8; ++q) { int x = i + 8 + q; c[q] = col[x < e ? x : e - 1]; }
      #pragma unroll
      for (int z = 0; z < 8; ++z)
        acc[z] += (((float)v[0][z] + (float)v[1][z]) + ((float)v[2][z] + (float)v[3][z])) +
                  (((float)v[4][z] + (float)v[5][z]) + ((float)v[6][z] + (float)v[7][z]));
    }
    if (i < e) {  // masked tail, c[] holds clamped indices
      f16x8 v[8];
      #pragma unroll
      for (int q = 0; q < 8; ++q) v[q] = *(const f16x8*)(hb + ((((unsigned)c[q]) << 6) | lofs));
      #pragma unroll
      for (int q = 0; q < 8; ++q) {
        float m = (i + q < e) ? 1.f : 0.f;
        #pragma unroll
        for (int z = 0; z < 8; ++z) acc[z] = fmaf(m, (float)v[q][z], acc[z]);
      }
    }
  }
  f16x8 o;
  #pragma unroll
  for (int q = 0; q < 8; ++q) o[q] = (_Float16)acc[q];
  *(f16x8*)(aggplanes + (size_t)pass * planeN + (size_t)row * 32 + lq * 8) = o;
}

// ---------------- dense GEMM over planes: out = relu(concat[agg,h] @ Wcat + b*bscale) ----------------
__global__ __launch_bounds__(256) void gemm_kernel(const _Float16* __restrict__ aggp,
                                                   const _Float16* __restrict__ hp,
                                                   const _Float16* __restrict__ Whi,
                                                   const _Float16* __restrict__ Wlo,
                                                   const float* __restrict__ bias,
                                                   float bscale,
                                                   _Float16* __restrict__ outp, int N) {
  size_t planeN = (size_t)N * 32;
  int wv = threadIdx.x >> 6;
  int lane = threadIdx.x & 63;
  int l16 = lane & 15;
  int khalf = lane >> 4;  // 0..3
  int koff = khalf * 8;
  int row_base = blockIdx.x * 64;
  int col_base = wv * 32;

  f32x4 acc[4][2];
  #pragma unroll
  for (int r = 0; r < 4; r++)
    #pragma unroll
    for (int c = 0; c < 2; c++) acc[r][c] = (f32x4){0.f, 0.f, 0.f, 0.f};

  #pragma unroll
  for (int ks = 0; ks < 8; ++ks) {
    int k0 = ks * 32;
    const _Float16* Abase = (ks < 4) ? (aggp + (size_t)ks * planeN)
                                     : (hp + (size_t)(ks - 4) * planeN);
    f16x8 bh[2], bl[2];
    #pragma unroll
    for (int c = 0; c < 2; c++) {
      int col = col_base + c * 16 + l16;
      bh[c] = *(const f16x8*)(Whi + col * 256 + k0 + koff);
      bl[c] = *(const f16x8*)(Wlo + col * 256 + k0 + koff);
    }
    #pragma unroll
    for (int r = 0; r < 4; r++) {
      int row = row_base + r * 16 + l16;
      if (row >= N) row = N - 1;
      f16x8 a = *(const f16x8*)(Abase + (size_t)row * 32 + koff);
      #pragma unroll
      for (int c = 0; c < 2; c++) {
        acc[r][c] = __builtin_amdgcn_mfma_f32_16x16x32_f16(a, bh[c], acc[r][c], 0, 0, 0);
        acc[r][c] = __builtin_amdgcn_mfma_f32_16x16x32_f16(a, bl[c], acc[r][c], 0, 0, 0);
      }
    }
  }

  #pragma unroll
  for (int r = 0; r < 4; r++) {
    #pragma unroll
    for (int c = 0; c < 2; c++) {
      int cc = col_base + c * 16 + l16;
      float b = bias[cc] * bscale;
      #pragma unroll
      for (int tt = 0; tt < 4; tt++) {
        int row = row_base + r * 16 + khalf * 4 + tt;
        if (row < N) {
          float v = acc[r][c][tt] + b;
          outp[(size_t)wv * planeN + (size_t)row * 32 + (c * 16 + l16)] =
              (_Float16)(v > 0.f ? v : 0.f);
        }
      }
    }
  }
}

// ---------------- fused pool + MLP head (batch sorted, plane reads) ----------------
static __device__ __forceinline__ int lbound(const int* __restrict__ a, int n, int v) {
  int lo = 0, hi = n;
  while (lo < hi) {
    int m = (lo + hi) >> 1;
    if (a[m] < v) lo = m + 1; else hi = m;
  }
  return lo;
}

__global__ __launch_bounds__(128) void poolhead_kernel(const _Float16* __restrict__ h,
                                                       const int* __restrict__ batch,
                                                       const float* __restrict__ fc1W,
                                                       const float* __restrict__ fc1b,
                                                       const float* __restrict__ fc2W,
                                                       const float* __restrict__ fc2b,
                                                       float* __restrict__ out, int N,
                                                       float unscale) {
  int gid = blockIdx.x, j = threadIdx.x;
  int start = lbound(batch, N, gid);
  int end = lbound(batch, N, gid + 1);
  size_t planeN = (size_t)N * 32;
  const _Float16* __restrict__ base = h + (size_t)(j >> 5) * planeN + (j & 31);
  float acc = 0.f;
  int r = start;
  for (; r + 3 < end; r += 4) {
    acc += (float)base[(size_t)r * 32] + (float)base[(size_t)(r + 1) * 32] +
           (float)base[(size_t)(r + 2) * 32] + (float)base[(size_t)(r + 3) * 32];
  }
  for (; r < end; ++r) acc += (float)base[(size_t)r * 32];
  __shared__ float grow[128];
  __shared__ float red[128];
  grow[j] = acc * unscale;
  __syncthreads();
  float a1 = fc1b[j];
  #pragma unroll 8
  for (int k = 0; k < 128; ++k) a1 = fmaf(grow[k], fc1W[k * 128 + j], a1);
  a1 = a1 > 0.f ? a1 : 0.f;
  red[j] = a1 * fc2W[j];
  __syncthreads();
  #pragma unroll
  for (int s2 = 64; s2 > 0; s2 >>= 1) {
    if (j < s2) red[j] += red[j + s2];
    __syncthreads();
  }
  if (j == 0) out[gid] = red[0] + fc2b[0];
}

extern "C" void kernel_launch(void* const* d_in, const int* in_sizes, int n_in,
                              void* d_out, int out_size, void* d_ws, size_t ws_size,
                              hipStream_t stream) {
  const float* x = (const float*)d_in[0];
  const int* edge = (const int*)d_in[1];
  const int* batch = (const int*)d_in[2];
  const int N = in_sizes[0] / 128;
  const int E = in_sizes[1] / 2;
  const int G = out_size;
  const int* esrc = edge;
  const int* edst = edge + E;
  const int NB = (N + 127) >> BSH;  // buckets
  const int nb1 = (E + CHUNK - 1) / CHUNK;

  char* ws = (char*)d_ws;
  size_t off = 0;
  auto alloc = [&](size_t bytes) -> void* {
    void* p = ws + off;
    off = (off + bytes + 255) & ~(size_t)255;
    return p;
  };
  _Float16* x16  = (_Float16*)alloc((size_t)N * 128 * 2);
  _Float16* bufA = (_Float16*)alloc((size_t)N * 128 * 2);
  _Float16* bufB = (_Float16*)alloc((size_t)N * 128 * 2);
  _Float16* agg  = (_Float16*)alloc((size_t)N * 128 * 2);
  _Float16* Whi  = (_Float16*)alloc((size_t)5 * 32768 * 2);
  _Float16* Wlo  = (_Float16*)alloc((size_t)5 * 32768 * 2);
  int* row_ptr   = (int*)alloc((size_t)(N + 1) * 4);
  int* col       = (int*)alloc((size_t)E * 4);
  int2* pairs    = (int2*)alloc((size_t)E * 8);
  int* blkhist   = (int*)alloc((size_t)nb1 * 512 * 4);
  int* base      = (int*)alloc(520 * 4);
  int* gcursor   = (int*)alloc(512 * 4);
  if (off > ws_size) return;  // fail loudly

  bhist_kernel<<<nb1, 256, 0, stream>>>(edst, blkhist, E, NB);
  bscan_kernel<<<1, 512, 0, stream>>>(blkhist, nb1, base, gcursor, NB, E);
  bscatter_kernel<<<nb1, 256, 0, stream>>>(esrc, edst, gcursor, pairs, E, NB);
  bbuild_kernel<<<NB, 256, 0, stream>>>(pairs, base, row_ptr, col, N, E);

  cvt_kernel<<<(N * 32 + 255) / 256, 256, 0, stream>>>(x, x16, N);

  // h'_l = h_l / 8^l keeps fp16 in range; weights *1/8, bias *8^-(l+1), undone at pool.
  const float S = 8.0f;
  W10 wp;
  for (int l = 0; l < 5; ++l) {
    wp.p[l] = (const float*)d_in[4 + 3 * l];
    wp.p[5 + l] = (const float*)d_in[6 + 3 * l];
  }
  prep_kernel<<<640, 256, 0, stream>>>(wp, Whi, Wlo, 1.0f / S);

  const _Float16* hin = x16;
  _Float16* hout = bufA;
  int nbpp = (N + 63) / 64;           // blocks per pass
  int gemm_grid = (N + 63) / 64;
  float bscale = 1.0f;
  for (int l = 0; l < 5; ++l) {
    bscale /= S;
    spmm_kernel<<<4 * nbpp, 256, 0, stream>>>(hin, row_ptr, col, agg, N, nbpp);
    gemm_kernel<<<gemm_grid, 256, 0, stream>>>(agg, hin,
                                               Whi + (size_t)l * 32768, Wlo + (size_t)l * 32768,
                                               (const float*)d_in[5 + 3 * l], bscale, hout, N);
    hin = hout;
    hout = (hout == bufA) ? bufB : bufA;
  }
  poolhead_kernel<<<G, 128, 0, stream>>>(hin, batch,
                                         (const float*)d_in[19], (const float*)d_in[20],
                                         (const float*)d_in[21], (const float*)d_in[22],
                                         (float*)d_out, N, 32768.0f);
}